// Round 11
// baseline (492.596 us; speedup 1.0000x reference)
//
#include <hip/hip_runtime.h>
#include <hip/hip_fp16.h>
#include <stdint.h>

typedef _Float16 f16_t;
typedef _Float16 f16x8 __attribute__((ext_vector_type(8)));
typedef float f32x4 __attribute__((ext_vector_type(4)));

// ---- helpers: fp16 pack/unpack ----
__device__ __forceinline__ unsigned int pack_h2(float a, float b) {
    return (unsigned int)__half_as_ushort(__float2half(a)) |
           ((unsigned int)__half_as_ushort(__float2half(b)) << 16);
}
__device__ __forceinline__ float4 cvt_h4(uint2 r) {
    __half2 h0 = *reinterpret_cast<__half2*>(&r.x);
    __half2 h1 = *reinterpret_cast<__half2*>(&r.y);
    float2 f0 = __half22float2(h0), f1 = __half22float2(h1);
    return make_float4(f0.x, f0.y, f1.x, f1.y);
}

// ---------------- weight prep: W[K][COUT] fp32 -> B fragment-ordered fp16 ----------------
// Layout: B[t][kb][lane][e]  (t = 16-col tile incl. sd tile, kb = 32-k block,
// lane = kg*16+col, e = 0..7; element = W[kb*32+kg*8+e][t*16+col]).
// sd fold: cols COUT..COUT+H-1 = W@asrc per head; COUT+H..COUT+2H-1 = W@adst; rest 0.
__global__ __launch_bounds__(256) void prep_kernel(
    const float* __restrict__ W1m, const float* __restrict__ as1m, const float* __restrict__ ad1m,
    const float* __restrict__ W1p, const float* __restrict__ as1p, const float* __restrict__ ad1p,
    const float* __restrict__ W2m, const float* __restrict__ as2m, const float* __restrict__ ad2m,
    const float* __restrict__ W2p, const float* __restrict__ as2p, const float* __restrict__ ad2p,
    const float* __restrict__ Wdm, const float* __restrict__ Wdp,
    f16_t* __restrict__ B1m, f16_t* __restrict__ B1p,
    f16_t* __restrict__ B2m, f16_t* __restrict__ B2p,
    f16_t* __restrict__ Bdm, f16_t* __restrict__ Bdp)
{
    const float *W = nullptr, *as = nullptr, *ad = nullptr;
    f16_t* B = nullptr; int K = 0, COUT = 0, H = 0;
    switch (blockIdx.x) {
        case 0: W = W1m; as = as1m; ad = ad1m; B = B1m; K = 128; COUT = 128; H = 4; break;
        case 1: W = W1p; as = as1p; ad = ad1p; B = B1p; K = 128; COUT = 128; H = 4; break;
        case 2: W = W2m; as = as2m; ad = ad2m; B = B2m; K = 128; COUT = 64;  H = 1; break;
        case 3: W = W2p; as = as2p; ad = ad2p; B = B2p; K = 128; COUT = 64;  H = 1; break;
        case 4: W = Wdm; B = Bdm; K = 64; COUT = 128; H = 0; break;
        case 5: W = Wdp; B = Bdp; K = 64; COUT = 128; H = 0; break;
    }
    const int KB = K / 32;
    const int TT = (COUT + 16) / 16;
    const int total = TT * KB * 512;              // == (COUT+16)*K
    for (int idx = threadIdx.x; idx < total; idx += 256) {
        int t    = idx / (KB * 512);
        int r    = idx - t * (KB * 512);
        int kb   = r >> 9;
        int r2   = r & 511;
        int lane = r2 >> 3, e = r2 & 7;
        int col  = lane & 15, kg = lane >> 4;
        int k    = kb * 32 + kg * 8 + e;
        int c    = t * 16 + col;
        float v = 0.f;
        if (c < COUT) {
            v = W[(size_t)k * COUT + c];
        } else {
            int ee = c - COUT;
            if (H > 0 && ee < 2 * H) {
                int h = (ee < H) ? ee : ee - H;
                const float* av = (ee < H) ? as : ad;
                int CH = COUT / H;
                for (int cc = 0; cc < CH; ++cc)
                    v += W[(size_t)k * COUT + h * CH + cc] * av[h * CH + cc];
            }
        }
        B[idx] = (f16_t)v;
    }
}

// ---------------- MFMA GEMM: out[n,COUT] = X[n,K] @ W  (+bias), fp32 acc ----------------
// 4 waves/block, each wave = 32 rows (2 A-frags) x COUT. No LDS. B fragment-ordered
// (coalesced 1-KB loads, shared across both row-frags). SDH>0: extra tile = s|d.
template<int K, int COUT, bool IN_HALF, bool OUT_HALF, int SDH, bool ADD_BIAS>
__global__ __launch_bounds__(256) void mfma_gemm(const void* __restrict__ X0,
                                                 const void* __restrict__ X1,
                                                 const f16_t* __restrict__ B0,
                                                 const f16_t* __restrict__ B1,
                                                 const float* __restrict__ b0,
                                                 const float* __restrict__ b1,
                                                 float* __restrict__ s_out,
                                                 float* __restrict__ d_out,
                                                 void* __restrict__ out0,
                                                 void* __restrict__ out1, int n)
{
    constexpr int NT = COUT / 16;                 // output col-tiles
    constexpr int TT = NT + ((SDH > 0) ? 1 : 0);  // + sd tile
    constexpr int KB = K / 32;

    const int side = blockIdx.y;
    const void*  Xv = side ? X1 : X0;
    const f16_t* B  = side ? B1 : B0;
    const float* bias = side ? b1 : b0;
    void* outp = side ? out1 : out0;

    const int wid  = threadIdx.x >> 6;
    const int lane = threadIdx.x & 63;
    const int r0 = blockIdx.x * 128 + wid * 32;
    if (r0 >= n) return;
    const int col = lane & 15;
    const int kg  = lane >> 4;                    // k-chunk 0..3 (8 f16 each)
    const int ar0 = min(r0 + col, n - 1);
    const int ar1 = min(r0 + 16 + col, n - 1);

    f32x4 acc[2][TT];
    #pragma unroll
    for (int h = 0; h < 2; ++h)
        #pragma unroll
        for (int t = 0; t < TT; ++t) acc[h][t] = (f32x4)0.f;

    #pragma unroll
    for (int kb = 0; kb < KB; ++kb) {
        f16x8 a0, a1;
        if constexpr (IN_HALF) {
            a0 = *reinterpret_cast<const f16x8*>((const f16_t*)Xv + (size_t)ar0 * K + kb * 32 + kg * 8);
            a1 = *reinterpret_cast<const f16x8*>((const f16_t*)Xv + (size_t)ar1 * K + kb * 32 + kg * 8);
        } else {
            const float* x0 = (const float*)Xv + (size_t)ar0 * K + kb * 32 + kg * 8;
            const float* x1 = (const float*)Xv + (size_t)ar1 * K + kb * 32 + kg * 8;
            float4 u0 = *reinterpret_cast<const float4*>(x0);
            float4 w0 = *reinterpret_cast<const float4*>(x0 + 4);
            float4 u1 = *reinterpret_cast<const float4*>(x1);
            float4 w1 = *reinterpret_cast<const float4*>(x1 + 4);
            a0[0] = (f16_t)u0.x; a0[1] = (f16_t)u0.y; a0[2] = (f16_t)u0.z; a0[3] = (f16_t)u0.w;
            a0[4] = (f16_t)w0.x; a0[5] = (f16_t)w0.y; a0[6] = (f16_t)w0.z; a0[7] = (f16_t)w0.w;
            a1[0] = (f16_t)u1.x; a1[1] = (f16_t)u1.y; a1[2] = (f16_t)u1.z; a1[3] = (f16_t)u1.w;
            a1[4] = (f16_t)w1.x; a1[5] = (f16_t)w1.y; a1[6] = (f16_t)w1.z; a1[7] = (f16_t)w1.w;
        }
        #pragma unroll
        for (int t = 0; t < TT; ++t) {
            f16x8 bf = *reinterpret_cast<const f16x8*>(B + ((size_t)(t * KB + kb) * 64 + lane) * 8);
            acc[0][t] = __builtin_amdgcn_mfma_f32_16x16x32_f16(a0, bf, acc[0][t], 0, 0, 0);
            acc[1][t] = __builtin_amdgcn_mfma_f32_16x16x32_f16(a1, bf, acc[1][t], 0, 0, 0);
        }
    }

    #pragma unroll
    for (int h = 0; h < 2; ++h) {
        const int rb = r0 + h * 16 + 4 * kg;      // this frag's 4 output rows
        #pragma unroll
        for (int t = 0; t < NT; ++t) {
            float bv = 0.f;
            if constexpr (ADD_BIAS) bv = bias[t * 16 + col];
            #pragma unroll
            for (int j = 0; j < 4; ++j) {
                int row = rb + j;
                if (row < n) {
                    float v = acc[h][t][j] + bv;
                    if constexpr (OUT_HALF)
                        ((__half*)outp)[(size_t)row * COUT + t * 16 + col] = __float2half(v);
                    else
                        ((float*)outp)[(size_t)row * COUT + t * 16 + col] = v;
                }
            }
        }
        if constexpr (SDH > 0) {
            #pragma unroll
            for (int j = 0; j < 4; ++j) {
                int row = rb + j;
                if (row < n) {
                    float v = acc[h][NT][j];
                    size_t gi = (size_t)(side ? n + row : row) * SDH;
                    if (col < SDH) s_out[gi + col] = v;
                    else if (col < 2 * SDH) d_out[gi + (col - SDH)] = v;
                }
            }
        }
    }
}

// ---------------- bucketed CSR build ----------------
#define BSH 7
#define BCAP 2560     // mean 2048 entries/bucket, +11 sigma headroom
#define CHUNK_E 1024  // edges per block in phase 1 (782 blocks -> ~3 waves/SIMD; was 196 blocks)

__global__ __launch_bounds__(256) void bucket_scatter_kernel(const int* __restrict__ prov,
                                                             const int* __restrict__ memb,
                                                             int* __restrict__ bcnt,
                                                             int2* __restrict__ bstore,
                                                             int e, int n, int nbuck)
{
    __shared__ int hist[1024];
    __shared__ int lbase[1024];
    const int tid = threadIdx.x;
    const int e0 = blockIdx.x * CHUNK_E;
    const int e1 = min(e, e0 + CHUNK_E);

    for (int i = tid; i < nbuck; i += 256) hist[i] = 0;
    __syncthreads();
    for (int t = e0 + tid; t < e1; t += 256) {
        int m = memb[t], p = prov[t];
        atomicAdd(&hist[m >> BSH], 1);
        atomicAdd(&hist[(n + p) >> BSH], 1);
    }
    __syncthreads();
    for (int i = tid; i < nbuck; i += 256) {
        int h = hist[i];
        lbase[i] = (h > 0) ? atomicAdd(&bcnt[i], h) : 0;
        hist[i] = 0;   // reuse as intra-block cursor
    }
    __syncthreads();
    for (int t = e0 + tid; t < e1; t += 256) {
        int m = memb[t], p = prov[t];
        int b1 = m >> BSH;
        int pos1 = lbase[b1] + atomicAdd(&hist[b1], 1);
        if (pos1 < BCAP) bstore[(size_t)b1 * BCAP + pos1] = make_int2(m, p);
        int d2 = n + p;
        int b2 = d2 >> BSH;
        int pos2 = lbase[b2] + atomicAdd(&hist[b2], 1);
        if (pos2 < BCAP) bstore[(size_t)b2 * BCAP + pos2] = make_int2(d2, m);
    }
}

__global__ __launch_bounds__(1024) void bucket_scan_kernel(const int* __restrict__ bcnt,
                                                           int* __restrict__ bbase,
                                                           int* __restrict__ roff,
                                                           int nb, int n2)
{
    __shared__ int tmp[1024];
    int tid = threadIdx.x;
    int v = (tid < nb) ? min(bcnt[tid], BCAP) : 0;
    tmp[tid] = v; __syncthreads();
    for (int o = 1; o < 1024; o <<= 1) {
        int x = (tid >= o) ? tmp[tid - o] : 0;
        __syncthreads();
        tmp[tid] += x;
        __syncthreads();
    }
    bbase[tid] = tmp[tid] - v;          // exclusive bucket base
    if (tid == 0) roff[n2] = tmp[1023]; // total == 2E
}

__global__ __launch_bounds__(256) void bucket_build_kernel(const int* __restrict__ bcnt,
                                                           const int* __restrict__ bbase,
                                                           const int2* __restrict__ bstore,
                                                           int* __restrict__ roff,
                                                           int* __restrict__ colA,
                                                           int n2)
{
    __shared__ int2 ent[BCAP];
    __shared__ int  colL[BCAP];
    __shared__ int  cnts[128], pref[128], curs[128];

    const int b = blockIdx.x, tid = threadIdx.x;
    const int node0 = b << BSH;
    const int cnt  = min(bcnt[b], BCAP);
    const int base = bbase[b];

    if (tid < 128) cnts[tid] = 0;
    __syncthreads();
    for (int i = tid; i < cnt; i += 256) {
        int2 v = bstore[(size_t)b * BCAP + i];
        ent[i] = v;
        atomicAdd(&cnts[v.x - node0], 1);
    }
    __syncthreads();
    if (tid < 128) pref[tid] = cnts[tid];
    __syncthreads();
    #pragma unroll
    for (int o = 1; o < 128; o <<= 1) {
        int x = 0;
        if (tid < 128 && tid >= o) x = pref[tid - o];
        __syncthreads();
        if (tid < 128) pref[tid] += x;
        __syncthreads();
    }
    if (tid < 128) {
        int node = node0 + tid;
        if (node < n2) roff[node] = base + pref[tid] - cnts[tid];
        curs[tid] = 0;
    }
    __syncthreads();
    for (int i = tid; i < cnt; i += 256) {
        int2 v = ent[i];
        int loc = v.x - node0;
        int slot = (pref[loc] - cnts[loc]) + atomicAdd(&curs[loc], 1);
        colL[slot] = v.y;
    }
    __syncthreads();
    for (int i = tid; i < cnt; i += 256) colA[base + i] = colL[i];
}

// ---------------- alpha store helpers ----------------
template<int H>
__device__ __forceinline__ void store_alpha(__half* __restrict__ A, size_t e, const float* a) {
    if constexpr (H == 4) {
        uint2 w; w.x = pack_h2(a[0], a[1]); w.y = pack_h2(a[2], a[3]);
        *reinterpret_cast<uint2*>(A + e * 4) = w;
    } else {
        A[e] = __float2half(a[0]);
    }
}

// ---------------- full-wave alpha fallback (deg<=64 / deg>64) ----------------
template<int H>
__device__ __forceinline__ void alpha_one_fullwave(int iG, int lane,
                                                   const float* __restrict__ sarr,
                                                   const float* __restrict__ sb,
                                                   const float* __restrict__ darr,
                                                   const int* __restrict__ roff,
                                                   const int* __restrict__ col,
                                                   __half* __restrict__ A,
                                                   __half* __restrict__ aselfA)
{
    const int start = roff[iG], end = roff[iG + 1];
    const int deg = end - start;

    float dh[H], es[H];
    #pragma unroll
    for (int hh = 0; hh < H; ++hh) {
        dh[hh] = darr[(size_t)iG * H + hh];
        float e = sarr[(size_t)iG * H + hh] + dh[hh];
        es[hh] = fmaxf(e, 0.2f * e);
    }

    if (deg <= 64) {
        int srcL = (lane < deg) ? col[start + lane] : 0;
        float pl[H];
        if (lane < deg) {
            #pragma unroll
            for (int hh = 0; hh < H; ++hh) {
                float e = sb[(size_t)srcL * H + hh] + dh[hh];
                pl[hh] = __expf(fmaxf(e, 0.2f * e));
            }
        } else {
            #pragma unroll
            for (int hh = 0; hh < H; ++hh) pl[hh] = 0.f;
        }
        float zh[H];
        #pragma unroll
        for (int hh = 0; hh < H; ++hh) zh[hh] = pl[hh];
        #pragma unroll
        for (int hh = 0; hh < H; ++hh)
            for (int o = 32; o >= 1; o >>= 1)
                zh[hh] += __shfl_xor(zh[hh], o, 64);
        float av[H], sf[H];
        #pragma unroll
        for (int hh = 0; hh < H; ++hh) {
            float se = __expf(es[hh]);
            float invz = 1.f / (zh[hh] + se + 1e-16f);
            sf[hh] = se * invz;
            av[hh] = pl[hh] * invz;
        }
        if (lane < deg) store_alpha<H>(A, (size_t)(start + lane), av);
        if (lane == 0) store_alpha<H>(aselfA, (size_t)iG, sf);
        return;
    }

    // deg > 64: 2-pass (no max)
    float zh[H];
    #pragma unroll
    for (int hh = 0; hh < H; ++hh) zh[hh] = 0.f;
    for (int base = start; base < end; base += 64) {
        int idx = base + lane;
        if (idx < end) {
            int src = col[idx];
            #pragma unroll
            for (int hh = 0; hh < H; ++hh) {
                float e = sb[(size_t)src * H + hh] + dh[hh];
                e = fmaxf(e, 0.2f * e);
                zh[hh] += __expf(e);
            }
        }
    }
    #pragma unroll
    for (int hh = 0; hh < H; ++hh)
        for (int o = 32; o >= 1; o >>= 1)
            zh[hh] += __shfl_xor(zh[hh], o, 64);
    float invz[H], sf[H];
    #pragma unroll
    for (int hh = 0; hh < H; ++hh) {
        float se = __expf(es[hh]);
        invz[hh] = 1.f / (zh[hh] + se + 1e-16f);
        sf[hh] = se * invz[hh];
    }
    if (lane == 0) store_alpha<H>(aselfA, (size_t)iG, sf);
    for (int base = start; base < end; base += 64) {
        int idx = base + lane;
        if (idx < end) {
            int src = col[idx];
            float av[H];
            #pragma unroll
            for (int hh = 0; hh < H; ++hh) {
                float e = sb[(size_t)src * H + hh] + dh[hh];
                e = fmaxf(e, 0.2f * e);
                av[hh] = __expf(e) * invz[hh];
            }
            store_alpha<H>(A, (size_t)idx, av);
        }
    }
}

// ---------------- alpha kernel: softmax only, no LDS, grid-stride persistent ----------------
template<int H>
__global__ __launch_bounds__(256) void alpha_kernel(const float* __restrict__ sarr,
                                                    const float* __restrict__ darr,
                                                    const int* __restrict__ roff,
                                                    const int* __restrict__ col,
                                                    __half* __restrict__ A,
                                                    __half* __restrict__ aselfA, int N)
{
    const int n2 = 2 * N;
    const int lane = threadIdx.x & 63;
    const int g = lane >> 5, l = lane & 31;
    const int nw  = (gridDim.x * 256) >> 6;
    const int wv0 = (blockIdx.x * 256 + threadIdx.x) >> 6;
    const int npair = (n2 + 1) >> 1;

    for (int pr = wv0; pr < npair; pr += nw) {
        const int i0 = pr * 2;
        const bool nval = (i0 + g) < n2;
        const int iN = nval ? (i0 + g) : (n2 - 1);
        const int start = roff[iN], end = roff[iN + 1];
        const int deg = nval ? (end - start) : 0;
        const int degO = __shfl_xor(deg, 32, 64);

        if (max(deg, degO) <= 32) {
            const int side = (iN >= N) ? 1 : 0;
            const float* sb = sarr + (size_t)side * N * H;
            float dh[H], es[H];
            if constexpr (H == 4) {
                float4 dv = *reinterpret_cast<const float4*>(darr + (size_t)iN * 4);
                float4 sv = *reinterpret_cast<const float4*>(sarr + (size_t)iN * 4);
                dh[0] = dv.x; dh[1] = dv.y; dh[2] = dv.z; dh[3] = dv.w;
                float ev[4] = {sv.x + dv.x, sv.y + dv.y, sv.z + dv.z, sv.w + dv.w};
                #pragma unroll
                for (int hh = 0; hh < 4; ++hh) es[hh] = fmaxf(ev[hh], 0.2f * ev[hh]);
            } else {
                #pragma unroll
                for (int hh = 0; hh < H; ++hh) {
                    dh[hh] = darr[(size_t)iN * H + hh];
                    float e = sarr[(size_t)iN * H + hh] + dh[hh];
                    es[hh] = fmaxf(e, 0.2f * e);
                }
            }
            int srcL = (l < deg) ? col[start + l] : 0;
            float pl[H];
            if (l < deg) {
                if constexpr (H == 4) {
                    float4 sv = *reinterpret_cast<const float4*>(sb + (size_t)srcL * 4);
                    float ee[4] = {sv.x + dh[0], sv.y + dh[1], sv.z + dh[2], sv.w + dh[3]};
                    #pragma unroll
                    for (int hh = 0; hh < 4; ++hh) pl[hh] = __expf(fmaxf(ee[hh], 0.2f * ee[hh]));
                } else {
                    #pragma unroll
                    for (int hh = 0; hh < H; ++hh) {
                        float e = sb[(size_t)srcL * H + hh] + dh[hh];
                        pl[hh] = __expf(fmaxf(e, 0.2f * e));
                    }
                }
            } else {
                #pragma unroll
                for (int hh = 0; hh < H; ++hh) pl[hh] = 0.f;
            }
            float zh[H];
            #pragma unroll
            for (int hh = 0; hh < H; ++hh) zh[hh] = pl[hh];
            #pragma unroll
            for (int hh = 0; hh < H; ++hh)
                #pragma unroll
                for (int o = 16; o >= 1; o >>= 1)
                    zh[hh] += __shfl_xor(zh[hh], o, 64);   // stays within 32-lane group
            float av[H], sf[H];
            #pragma unroll
            for (int hh = 0; hh < H; ++hh) {
                float se = __expf(es[hh]);
                float invz = 1.f / (zh[hh] + se + 1e-16f);
                sf[hh] = se * invz;
                av[hh] = pl[hh] * invz;
            }
            if (l < deg) store_alpha<H>(A, (size_t)(start + l), av);
            if (l == 0 && nval) store_alpha<H>(aselfA, (size_t)iN, sf);
        } else {
            for (int nd = 0; nd < 2; ++nd) {
                int i = i0 + nd;
                if (i >= n2) break;
                int sd2 = (i >= N) ? 1 : 0;
                alpha_one_fullwave<H>(i, lane, sarr, sarr + (size_t)sd2 * N * H, darr,
                                      roff, col, A, aselfA);
            }
        }
    }
}

// ---------------- gather kernel: ONE node per 64-lane wave, grid-stride persistent ----------
// C=128: 16 lanes/row, 4 edges in parallel; C=64: 8 lanes/row, 8 edges in parallel.
// vs the 2-nodes-per-wave version: no pair-imbalance (cost was E[max(d1,d2)]), 2x edges
// in flight per node, final xor-reduce extends to o=16,32 on the converged wave.
template<int C, int H, bool ELU, bool OUTH>
__global__ __launch_bounds__(256) void gather_kernel(const __half* __restrict__ hm,
                                                     const __half* __restrict__ hp,
                                                     const __half* __restrict__ A,
                                                     const __half* __restrict__ aselfA,
                                                     const int* __restrict__ roff,
                                                     const int* __restrict__ col,
                                                     const float* __restrict__ bias_m,
                                                     const float* __restrict__ bias_p,
                                                     void* __restrict__ out_m,
                                                     void* __restrict__ out_p, int N)
{
    constexpr int CH  = C / H;
    constexpr int LRd = C / 8;        // lanes per row (16 for C=128, 8 for C=64)
    constexpr int EP  = 64 / LRd;     // edges in parallel (4 or 8)
    const int n2 = 2 * N;
    const int lane = threadIdx.x & 63;
    const int sub = lane / LRd, q = lane % LRd;
    const int c0 = q * 8;
    const int hd = c0 / CH;
    const int nw  = (gridDim.x * 256) >> 6;
    const int wv0 = (blockIdx.x * 256 + threadIdx.x) >> 6;

    for (int iN = wv0; iN < n2; iN += nw) {
        const int side = (iN >= N) ? 1 : 0;
        const int lN = iN - side * N;
        const __half* hf = side ? hp : hm;
        const int start = roff[iN];
        const int deg = roff[iN + 1] - start;

        float acc[8];
        #pragma unroll
        for (int j = 0; j < 8; ++j) acc[j] = 0.f;
        if (sub == 0) {
            uint4 r = *reinterpret_cast<const uint4*>(hf + (size_t)lN * C + c0);
            float4 lo = cvt_h4(make_uint2(r.x, r.y));
            float4 hi = cvt_h4(make_uint2(r.z, r.w));
            float a = __half2float(aselfA[(size_t)iN * H + hd]);
            acc[0] = a * lo.x; acc[1] = a * lo.y; acc[2] = a * lo.z; acc[3] = a * lo.w;
            acc[4] = a * hi.x; acc[5] = a * hi.y; acc[6] = a * hi.z; acc[7] = a * hi.w;
        }
        int t = sub;
#define GSTEP(U)                                                                     \
        while (t + (U - 1) * EP < deg) {                                             \
            int ss[U]; float aa[U]; uint4 rr[U];                                     \
            _Pragma("unroll")                                                        \
            for (int u = 0; u < U; ++u) {                                            \
                int e = start + t + u * EP;                                          \
                ss[u] = col[e];                                                      \
                aa[u] = __half2float(A[(size_t)e * H + hd]);                         \
            }                                                                        \
            _Pragma("unroll")                                                        \
            for (int u = 0; u < U; ++u)                                              \
                rr[u] = *reinterpret_cast<const uint4*>(hf + (size_t)ss[u] * C + c0); \
            _Pragma("unroll")                                                        \
            for (int u = 0; u < U; ++u) {                                            \
                float4 lo = cvt_h4(make_uint2(rr[u].x, rr[u].y));                    \
                float4 hi = cvt_h4(make_uint2(rr[u].z, rr[u].w));                    \
                acc[0] = fmaf(aa[u], lo.x, acc[0]);                                  \
                acc[1] = fmaf(aa[u], lo.y, acc[1]);                                  \
                acc[2] = fmaf(aa[u], lo.z, acc[2]);                                  \
                acc[3] = fmaf(aa[u], lo.w, acc[3]);                                  \
                acc[4] = fmaf(aa[u], hi.x, acc[4]);                                  \
                acc[5] = fmaf(aa[u], hi.y, acc[5]);                                  \
                acc[6] = fmaf(aa[u], hi.z, acc[6]);                                  \
                acc[7] = fmaf(aa[u], hi.w, acc[7]);                                  \
            }                                                                        \
            t += U * EP;                                                             \
        }
        GSTEP(4)
        GSTEP(2)
        GSTEP(1)
#undef GSTEP
        // cross-sub reduce across the (now converged) wave
        #pragma unroll
        for (int o = LRd; o < 64; o <<= 1) {
            #pragma unroll
            for (int j = 0; j < 8; ++j) acc[j] += __shfl_xor(acc[j], o, 64);
        }
        if (sub == 0) {
            const float* biasS = side ? bias_p : bias_m;
            float4 b0 = *reinterpret_cast<const float4*>(biasS + c0);
            float4 b1 = *reinterpret_cast<const float4*>(biasS + c0 + 4);
            float v[8] = {acc[0] + b0.x, acc[1] + b0.y, acc[2] + b0.z, acc[3] + b0.w,
                          acc[4] + b1.x, acc[5] + b1.y, acc[6] + b1.z, acc[7] + b1.w};
            if constexpr (ELU) {
                #pragma unroll
                for (int j = 0; j < 8; ++j) v[j] = (v[j] > 0.f) ? v[j] : (__expf(v[j]) - 1.f);
            }
            if constexpr (OUTH) {
                __half* outS = (__half*)(side ? out_p : out_m);
                uint4 w;
                w.x = pack_h2(v[0], v[1]); w.y = pack_h2(v[2], v[3]);
                w.z = pack_h2(v[4], v[5]); w.w = pack_h2(v[6], v[7]);
                *reinterpret_cast<uint4*>(outS + (size_t)lN * C + c0) = w;
            } else {
                float* outS = (float*)(side ? out_p : out_m);
                float* po = outS + (size_t)lN * C + c0;
                *reinterpret_cast<float4*>(po)     = make_float4(v[0], v[1], v[2], v[3]);
                *reinterpret_cast<float4*>(po + 4) = make_float4(v[4], v[5], v[6], v[7]);
            }
        }
    }
}

// ---------------- edge logits: fp16 z, 8 lanes/edge (uint4), 2x unrolled ----------------
__global__ __launch_bounds__(256) void logits_kernel(const __half* __restrict__ zp,
                                                     const __half* __restrict__ zm,
                                                     const int* __restrict__ prov,
                                                     const int* __restrict__ memb,
                                                     float* __restrict__ outv, int e)
{
    const int nw   = (gridDim.x * 256) >> 6;
    const int wv   = (blockIdx.x * 256 + threadIdx.x) >> 6;
    const int lane = threadIdx.x & 63;
    const int g = lane >> 3, q = lane & 7;     // 8 edges/wave, 8 lanes/edge, 8 ch/lane
    const int c0 = q * 8;
    for (int base = wv * 16; base < e; base += nw * 16) {
        int e1 = base + g, e2 = base + 8 + g;
        bool v1 = e1 < e, v2 = e2 < e;
        int i1 = v1 ? e1 : (e - 1), i2 = v2 ? e2 : (e - 1);
        int p1 = prov[i1], m1 = memb[i1];
        int p2 = prov[i2], m2 = memb[i2];
        uint4 a1 = *reinterpret_cast<const uint4*>(zp + (size_t)p1 * 64 + c0);
        uint4 b1 = *reinterpret_cast<const uint4*>(zm + (size_t)m1 * 64 + c0);
        uint4 a2 = *reinterpret_cast<const uint4*>(zp + (size_t)p2 * 64 + c0);
        uint4 b2 = *reinterpret_cast<const uint4*>(zm + (size_t)m2 * 64 + c0);
        float4 al1 = cvt_h4(make_uint2(a1.x, a1.y)), ah1 = cvt_h4(make_uint2(a1.z, a1.w));
        float4 bl1 = cvt_h4(make_uint2(b1.x, b1.y)), bh1 = cvt_h4(make_uint2(b1.z, b1.w));
        float4 al2 = cvt_h4(make_uint2(a2.x, a2.y)), ah2 = cvt_h4(make_uint2(a2.z, a2.w));
        float4 bl2 = cvt_h4(make_uint2(b2.x, b2.y)), bh2 = cvt_h4(make_uint2(b2.z, b2.w));
        float s1 = al1.x * bl1.x + al1.y * bl1.y + al1.z * bl1.z + al1.w * bl1.w
                 + ah1.x * bh1.x + ah1.y * bh1.y + ah1.z * bh1.z + ah1.w * bh1.w;
        float s2 = al2.x * bl2.x + al2.y * bl2.y + al2.z * bl2.z + al2.w * bl2.w
                 + ah2.x * bh2.x + ah2.y * bh2.y + ah2.z * bh2.z + ah2.w * bh2.w;
        #pragma unroll
        for (int o = 1; o < 8; o <<= 1) {
            s1 += __shfl_xor(s1, o, 64);
            s2 += __shfl_xor(s2, o, 64);
        }
        if (q == 0) {
            if (v1) outv[e1] = s1;
            if (v2) outv[e2] = s2;
        }
    }
}

// ---------------- launch ----------------
extern "C" void kernel_launch(void* const* d_in, const int* in_sizes, int n_in,
                              void* d_out, int out_size, void* d_ws, size_t ws_size,
                              hipStream_t stream)
{
    const int N_ = in_sizes[0] / 128;
    const int E_ = in_sizes[2] / 2;

    const float* x_member   = (const float*)d_in[0];
    const float* x_provider = (const float*)d_in[1];
    const int*   prov = (const int*)d_in[2];
    const int*   memb = prov + E_;
    const float* W1_m = (const float*)d_in[3];
    const float* a_src1_m = (const float*)d_in[4];
    const float* a_dst1_m = (const float*)d_in[5];
    const float* b1_m = (const float*)d_in[6];
    const float* W2_m = (const float*)d_in[7];
    const float* a_src2_m = (const float*)d_in[8];
    const float* a_dst2_m = (const float*)d_in[9];
    const float* b2_m = (const float*)d_in[10];
    const float* W1_p = (const float*)d_in[11];
    const float* a_src1_p = (const float*)d_in[12];
    const float* a_dst1_p = (const float*)d_in[13];
    const float* b1_p = (const float*)d_in[14];
    const float* W2_p = (const float*)d_in[15];
    const float* a_src2_p = (const float*)d_in[16];
    const float* a_dst2_p = (const float*)d_in[17];
    const float* b2_p = (const float*)d_in[18];
    const float* Wd_m = (const float*)d_in[19];
    const float* bd_m = (const float*)d_in[20];
    const float* Wd_p = (const float*)d_in[21];
    const float* bd_p = (const float*)d_in[22];

    const int n2 = 2 * N_;
    const int NB = (n2 + 127) >> BSH;           // 782 buckets

    char* p = (char*)d_ws;
    auto alloc = [&](size_t bytes) { void* q = (void*)p; p += (bytes + 255) & ~(size_t)255; return q; };
    // h1m/h1p contiguous: bstore (16 MB) overlays both (25.6 MB) during CSR build.
    __half* h1m   = (__half*)alloc((size_t)N_ * 128 * 2);
    __half* h1p   = (__half*)alloc((size_t)N_ * 128 * 2);
    __half* xm16m = (__half*)alloc((size_t)N_ * 128 * 2);
    __half* xm16p = (__half*)alloc((size_t)N_ * 128 * 2);
    __half* zm16  = (__half*)alloc((size_t)N_ * 64 * 2);   // layer-2 output; alpha1 overlay
    __half* zp16  = (__half*)alloc((size_t)N_ * 64 * 2);
    float* s1     = (float*)alloc((size_t)n2 * 4 * 4);     // also reused for layer-2 s (H=1)
    float* d1     = (float*)alloc((size_t)n2 * 4 * 4);
    __half* alpha2= (__half*)alloc((size_t)2 * E_ * 2);    // layer-2 per-edge alpha (H=1)
    __half* aselfH= (__half*)alloc((size_t)n2 * 4 * 2);    // per-node self alpha (H<=4)
    int*   bcnt   = (int*)alloc((size_t)NB * 4);
    int*   bbase  = (int*)alloc(1024 * 4);
    int*   roff2  = (int*)alloc((size_t)(n2 + 1) * 4);
    int*   colA   = (int*)alloc((size_t)2 * E_ * 4);
    // prepped fp16 weights (fragment-ordered, + folded sd columns)
    f16_t* B1m = (f16_t*)alloc((size_t)(128 + 16) * 128 * 2);
    f16_t* B1p = (f16_t*)alloc((size_t)(128 + 16) * 128 * 2);
    f16_t* B2m = (f16_t*)alloc((size_t)(64 + 16) * 128 * 2);
    f16_t* B2p = (f16_t*)alloc((size_t)(64 + 16) * 128 * 2);
    f16_t* Bdm = (f16_t*)alloc((size_t)(128 + 16) * 64 * 2);
    f16_t* Bdp = (f16_t*)alloc((size_t)(128 + 16) * 64 * 2);
    __half* h2m = h1m;                           // overlay: h1 dead after gather1 (6.4 <= 12.8 MB)
    __half* h2p = h1p;
    int2*  bstore = (int2*)h1m;                  // overlay: dead before gemm1 writes h1
    __half* alpha1 = zm16;                       // overlay: zm16+zp16 (12.8 MB) dead until gather2;
                                                 // alpha1 = 2E*4 halves = 12.8 MB exactly

    // bucketed CSR build (both sides at once; dst ids: member v, provider N+v)
    hipMemsetAsync(bcnt, 0, (size_t)NB * 4, stream);
    bucket_scatter_kernel<<<(E_ + CHUNK_E - 1) / CHUNK_E, 256, 0, stream>>>(prov, memb, bcnt, bstore, E_, N_, NB);
    bucket_scan_kernel<<<1, 1024, 0, stream>>>(bcnt, bbase, roff2, NB, n2);
    bucket_build_kernel<<<NB, 256, 0, stream>>>(bcnt, bbase, bstore, roff2, colA, n2);

    // weight prep (tiny)
    prep_kernel<<<6, 256, 0, stream>>>(
        W1_m, a_src1_m, a_dst1_m, W1_p, a_src1_p, a_dst1_p,
        W2_m, a_src2_m, a_dst2_m, W2_p, a_src2_p, a_dst2_p,
        Wd_m, Wd_p, B1m, B1p, B2m, B2p, Bdm, Bdp);

    const dim3 gg((N_ + 127) / 128, 2);
    float* out = (float*)d_out;

    // layer 1: mfma gemm (sd folded into B) -> alpha -> gather
    mfma_gemm<128, 128, false, true, 4, false><<<gg, 256, 0, stream>>>(
        x_member, x_provider, B1m, B1p, nullptr, nullptr, s1, d1, h1m, h1p, N_);
    alpha_kernel<4><<<2048, 256, 0, stream>>>(s1, d1, roff2, colA, alpha1, aselfH, N_);
    gather_kernel<128, 4, true, true><<<2048, 256, 0, stream>>>(
        h1m, h1p, alpha1, aselfH, roff2, colA, b1_m, b1_p, xm16m, xm16p, N_);

    // layer 2: mfma gemm (sd folded, H=1) -> alpha -> gather
    mfma_gemm<128, 64, true, true, 1, false><<<gg, 256, 0, stream>>>(
        xm16m, xm16p, B2m, B2p, nullptr, nullptr, s1, d1, h2m, h2p, N_);
    alpha_kernel<1><<<2048, 256, 0, stream>>>(s1, d1, roff2, colA, alpha2, aselfH, N_);
    gather_kernel<64, 1, false, true><<<2048, 256, 0, stream>>>(
        h2m, h2p, alpha2, aselfH, roff2, colA, b2_m, b2_p, zm16, zp16, N_);

    // decoders (mfma, fp16 z input, fp32 out, +bias) + logits (fp16 z)
    mfma_gemm<64, 128, true, false, 0, true><<<gg, 256, 0, stream>>>(
        zm16, zp16, Bdm, Bdp, bd_m, bd_p, nullptr, nullptr,
        out, out + (size_t)N_ * 128, N_);
    logits_kernel<<<2048, 256, 0, stream>>>(zp16, zm16, prov, memb, out + (size_t)N_ * 128 * 2, E_);
}

// Round 12
// 457.927 us; speedup vs baseline: 1.0757x; 1.0757x over previous
//
#include <hip/hip_runtime.h>
#include <hip/hip_fp16.h>
#include <stdint.h>

typedef _Float16 f16_t;
typedef _Float16 f16x8 __attribute__((ext_vector_type(8)));
typedef float f32x4 __attribute__((ext_vector_type(4)));

// ---- helpers: fp16 pack/unpack ----
__device__ __forceinline__ unsigned int pack_h2(float a, float b) {
    return (unsigned int)__half_as_ushort(__float2half(a)) |
           ((unsigned int)__half_as_ushort(__float2half(b)) << 16);
}
__device__ __forceinline__ float4 cvt_h4(uint2 r) {
    __half2 h0 = *reinterpret_cast<__half2*>(&r.x);
    __half2 h1 = *reinterpret_cast<__half2*>(&r.y);
    float2 f0 = __half22float2(h0), f1 = __half22float2(h1);
    return make_float4(f0.x, f0.y, f1.x, f1.y);
}

// ---------------- weight prep: W[K][COUT] fp32 -> B fragment-ordered fp16 ----------------
// Layout: B[t][kb][lane][e]  (t = 16-col tile incl. sd tile, kb = 32-k block,
// lane = kg*16+col, e = 0..7; element = W[kb*32+kg*8+e][t*16+col]).
// sd fold: cols COUT..COUT+H-1 = W@asrc per head; COUT+H..COUT+2H-1 = W@adst; rest 0.
__global__ __launch_bounds__(256) void prep_kernel(
    const float* __restrict__ W1m, const float* __restrict__ as1m, const float* __restrict__ ad1m,
    const float* __restrict__ W1p, const float* __restrict__ as1p, const float* __restrict__ ad1p,
    const float* __restrict__ W2m, const float* __restrict__ as2m, const float* __restrict__ ad2m,
    const float* __restrict__ W2p, const float* __restrict__ as2p, const float* __restrict__ ad2p,
    const float* __restrict__ Wdm, const float* __restrict__ Wdp,
    f16_t* __restrict__ B1m, f16_t* __restrict__ B1p,
    f16_t* __restrict__ B2m, f16_t* __restrict__ B2p,
    f16_t* __restrict__ Bdm, f16_t* __restrict__ Bdp)
{
    const float *W = nullptr, *as = nullptr, *ad = nullptr;
    f16_t* B = nullptr; int K = 0, COUT = 0, H = 0;
    switch (blockIdx.x) {
        case 0: W = W1m; as = as1m; ad = ad1m; B = B1m; K = 128; COUT = 128; H = 4; break;
        case 1: W = W1p; as = as1p; ad = ad1p; B = B1p; K = 128; COUT = 128; H = 4; break;
        case 2: W = W2m; as = as2m; ad = ad2m; B = B2m; K = 128; COUT = 64;  H = 1; break;
        case 3: W = W2p; as = as2p; ad = ad2p; B = B2p; K = 128; COUT = 64;  H = 1; break;
        case 4: W = Wdm; B = Bdm; K = 64; COUT = 128; H = 0; break;
        case 5: W = Wdp; B = Bdp; K = 64; COUT = 128; H = 0; break;
    }
    const int KB = K / 32;
    const int TT = (COUT + 16) / 16;
    const int total = TT * KB * 512;              // == (COUT+16)*K
    for (int idx = threadIdx.x; idx < total; idx += 256) {
        int t    = idx / (KB * 512);
        int r    = idx - t * (KB * 512);
        int kb   = r >> 9;
        int r2   = r & 511;
        int lane = r2 >> 3, e = r2 & 7;
        int col  = lane & 15, kg = lane >> 4;
        int k    = kb * 32 + kg * 8 + e;
        int c    = t * 16 + col;
        float v = 0.f;
        if (c < COUT) {
            v = W[(size_t)k * COUT + c];
        } else {
            int ee = c - COUT;
            if (H > 0 && ee < 2 * H) {
                int h = (ee < H) ? ee : ee - H;
                const float* av = (ee < H) ? as : ad;
                int CH = COUT / H;
                for (int cc = 0; cc < CH; ++cc)
                    v += W[(size_t)k * COUT + h * CH + cc] * av[h * CH + cc];
            }
        }
        B[idx] = (f16_t)v;
    }
}

// ---------------- MFMA GEMM: out[n,COUT] = X[n,K] @ W  (+bias), fp32 acc ----------------
// 4 waves/block, each wave = 32 rows (2 A-frags) x COUT. No LDS. B fragment-ordered
// (coalesced 1-KB loads, shared across both row-frags). SDH>0: extra tile = s|d.
template<int K, int COUT, bool IN_HALF, bool OUT_HALF, int SDH, bool ADD_BIAS>
__global__ __launch_bounds__(256) void mfma_gemm(const void* __restrict__ X0,
                                                 const void* __restrict__ X1,
                                                 const f16_t* __restrict__ B0,
                                                 const f16_t* __restrict__ B1,
                                                 const float* __restrict__ b0,
                                                 const float* __restrict__ b1,
                                                 float* __restrict__ s_out,
                                                 float* __restrict__ d_out,
                                                 void* __restrict__ out0,
                                                 void* __restrict__ out1, int n)
{
    constexpr int NT = COUT / 16;                 // output col-tiles
    constexpr int TT = NT + ((SDH > 0) ? 1 : 0);  // + sd tile
    constexpr int KB = K / 32;

    const int side = blockIdx.y;
    const void*  Xv = side ? X1 : X0;
    const f16_t* B  = side ? B1 : B0;
    const float* bias = side ? b1 : b0;
    void* outp = side ? out1 : out0;

    const int wid  = threadIdx.x >> 6;
    const int lane = threadIdx.x & 63;
    const int r0 = blockIdx.x * 128 + wid * 32;
    if (r0 >= n) return;
    const int col = lane & 15;
    const int kg  = lane >> 4;                    // k-chunk 0..3 (8 f16 each)
    const int ar0 = min(r0 + col, n - 1);
    const int ar1 = min(r0 + 16 + col, n - 1);

    f32x4 acc[2][TT];
    #pragma unroll
    for (int h = 0; h < 2; ++h)
        #pragma unroll
        for (int t = 0; t < TT; ++t) acc[h][t] = (f32x4)0.f;

    #pragma unroll
    for (int kb = 0; kb < KB; ++kb) {
        f16x8 a0, a1;
        if constexpr (IN_HALF) {
            a0 = *reinterpret_cast<const f16x8*>((const f16_t*)Xv + (size_t)ar0 * K + kb * 32 + kg * 8);
            a1 = *reinterpret_cast<const f16x8*>((const f16_t*)Xv + (size_t)ar1 * K + kb * 32 + kg * 8);
        } else {
            const float* x0 = (const float*)Xv + (size_t)ar0 * K + kb * 32 + kg * 8;
            const float* x1 = (const float*)Xv + (size_t)ar1 * K + kb * 32 + kg * 8;
            float4 u0 = *reinterpret_cast<const float4*>(x0);
            float4 w0 = *reinterpret_cast<const float4*>(x0 + 4);
            float4 u1 = *reinterpret_cast<const float4*>(x1);
            float4 w1 = *reinterpret_cast<const float4*>(x1 + 4);
            a0[0] = (f16_t)u0.x; a0[1] = (f16_t)u0.y; a0[2] = (f16_t)u0.z; a0[3] = (f16_t)u0.w;
            a0[4] = (f16_t)w0.x; a0[5] = (f16_t)w0.y; a0[6] = (f16_t)w0.z; a0[7] = (f16_t)w0.w;
            a1[0] = (f16_t)u1.x; a1[1] = (f16_t)u1.y; a1[2] = (f16_t)u1.z; a1[3] = (f16_t)u1.w;
            a1[4] = (f16_t)w1.x; a1[5] = (f16_t)w1.y; a1[6] = (f16_t)w1.z; a1[7] = (f16_t)w1.w;
        }
        #pragma unroll
        for (int t = 0; t < TT; ++t) {
            f16x8 bf = *reinterpret_cast<const f16x8*>(B + ((size_t)(t * KB + kb) * 64 + lane) * 8);
            acc[0][t] = __builtin_amdgcn_mfma_f32_16x16x32_f16(a0, bf, acc[0][t], 0, 0, 0);
            acc[1][t] = __builtin_amdgcn_mfma_f32_16x16x32_f16(a1, bf, acc[1][t], 0, 0, 0);
        }
    }

    #pragma unroll
    for (int h = 0; h < 2; ++h) {
        const int rb = r0 + h * 16 + 4 * kg;      // this frag's 4 output rows
        #pragma unroll
        for (int t = 0; t < NT; ++t) {
            float bv = 0.f;
            if constexpr (ADD_BIAS) bv = bias[t * 16 + col];
            #pragma unroll
            for (int j = 0; j < 4; ++j) {
                int row = rb + j;
                if (row < n) {
                    float v = acc[h][t][j] + bv;
                    if constexpr (OUT_HALF)
                        ((__half*)outp)[(size_t)row * COUT + t * 16 + col] = __float2half(v);
                    else
                        ((float*)outp)[(size_t)row * COUT + t * 16 + col] = v;
                }
            }
        }
        if constexpr (SDH > 0) {
            #pragma unroll
            for (int j = 0; j < 4; ++j) {
                int row = rb + j;
                if (row < n) {
                    float v = acc[h][NT][j];
                    size_t gi = (size_t)(side ? n + row : row) * SDH;
                    if (col < SDH) s_out[gi + col] = v;
                    else if (col < 2 * SDH) d_out[gi + (col - SDH)] = v;
                }
            }
        }
    }
}

// ---------------- bucketed CSR build ----------------
#define BSH 7
#define BCAP 2560     // mean 2048 entries/bucket, +11 sigma headroom
#define CHUNK_E 1024  // edges per block in phase 1 (782 blocks -> ~3 waves/SIMD)

__global__ __launch_bounds__(256) void bucket_scatter_kernel(const int* __restrict__ prov,
                                                             const int* __restrict__ memb,
                                                             int* __restrict__ bcnt,
                                                             int2* __restrict__ bstore,
                                                             int e, int n, int nbuck)
{
    __shared__ int hist[1024];
    __shared__ int lbase[1024];
    const int tid = threadIdx.x;
    const int e0 = blockIdx.x * CHUNK_E;
    const int e1 = min(e, e0 + CHUNK_E);

    for (int i = tid; i < nbuck; i += 256) hist[i] = 0;
    __syncthreads();
    for (int t = e0 + tid; t < e1; t += 256) {
        int m = memb[t], p = prov[t];
        atomicAdd(&hist[m >> BSH], 1);
        atomicAdd(&hist[(n + p) >> BSH], 1);
    }
    __syncthreads();
    for (int i = tid; i < nbuck; i += 256) {
        int h = hist[i];
        lbase[i] = (h > 0) ? atomicAdd(&bcnt[i], h) : 0;
        hist[i] = 0;   // reuse as intra-block cursor
    }
    __syncthreads();
    for (int t = e0 + tid; t < e1; t += 256) {
        int m = memb[t], p = prov[t];
        int b1 = m >> BSH;
        int pos1 = lbase[b1] + atomicAdd(&hist[b1], 1);
        if (pos1 < BCAP) bstore[(size_t)b1 * BCAP + pos1] = make_int2(m, p);
        int d2 = n + p;
        int b2 = d2 >> BSH;
        int pos2 = lbase[b2] + atomicAdd(&hist[b2], 1);
        if (pos2 < BCAP) bstore[(size_t)b2 * BCAP + pos2] = make_int2(d2, m);
    }
}

__global__ __launch_bounds__(1024) void bucket_scan_kernel(const int* __restrict__ bcnt,
                                                           int* __restrict__ bbase,
                                                           int* __restrict__ roff,
                                                           int nb, int n2)
{
    __shared__ int tmp[1024];
    int tid = threadIdx.x;
    int v = (tid < nb) ? min(bcnt[tid], BCAP) : 0;
    tmp[tid] = v; __syncthreads();
    for (int o = 1; o < 1024; o <<= 1) {
        int x = (tid >= o) ? tmp[tid - o] : 0;
        __syncthreads();
        tmp[tid] += x;
        __syncthreads();
    }
    bbase[tid] = tmp[tid] - v;          // exclusive bucket base
    if (tid == 0) roff[n2] = tmp[1023]; // total == 2E
}

__global__ __launch_bounds__(256) void bucket_build_kernel(const int* __restrict__ bcnt,
                                                           const int* __restrict__ bbase,
                                                           const int2* __restrict__ bstore,
                                                           int* __restrict__ roff,
                                                           int* __restrict__ colA,
                                                           int n2)
{
    __shared__ int2 ent[BCAP];
    __shared__ int  colL[BCAP];
    __shared__ int  cnts[128], pref[128], curs[128];

    const int b = blockIdx.x, tid = threadIdx.x;
    const int node0 = b << BSH;
    const int cnt  = min(bcnt[b], BCAP);
    const int base = bbase[b];

    if (tid < 128) cnts[tid] = 0;
    __syncthreads();
    for (int i = tid; i < cnt; i += 256) {
        int2 v = bstore[(size_t)b * BCAP + i];
        ent[i] = v;
        atomicAdd(&cnts[v.x - node0], 1);
    }
    __syncthreads();
    if (tid < 128) pref[tid] = cnts[tid];
    __syncthreads();
    #pragma unroll
    for (int o = 1; o < 128; o <<= 1) {
        int x = 0;
        if (tid < 128 && tid >= o) x = pref[tid - o];
        __syncthreads();
        if (tid < 128) pref[tid] += x;
        __syncthreads();
    }
    if (tid < 128) {
        int node = node0 + tid;
        if (node < n2) roff[node] = base + pref[tid] - cnts[tid];
        curs[tid] = 0;
    }
    __syncthreads();
    for (int i = tid; i < cnt; i += 256) {
        int2 v = ent[i];
        int loc = v.x - node0;
        int slot = (pref[loc] - cnts[loc]) + atomicAdd(&curs[loc], 1);
        colL[slot] = v.y;
    }
    __syncthreads();
    for (int i = tid; i < cnt; i += 256) colA[base + i] = colL[i];
}

// ---------------- alpha store helpers ----------------
template<int H>
__device__ __forceinline__ void store_alpha(__half* __restrict__ A, size_t e, const float* a) {
    if constexpr (H == 4) {
        uint2 w; w.x = pack_h2(a[0], a[1]); w.y = pack_h2(a[2], a[3]);
        *reinterpret_cast<uint2*>(A + e * 4) = w;
    } else {
        A[e] = __float2half(a[0]);
    }
}

// ---------------- full-wave alpha fallback (deg<=64 / deg>64) ----------------
template<int H>
__device__ __forceinline__ void alpha_one_fullwave(int iG, int lane,
                                                   const float* __restrict__ sarr,
                                                   const float* __restrict__ sb,
                                                   const float* __restrict__ darr,
                                                   const int* __restrict__ roff,
                                                   const int* __restrict__ col,
                                                   __half* __restrict__ A,
                                                   __half* __restrict__ aselfA)
{
    const int start = roff[iG], end = roff[iG + 1];
    const int deg = end - start;

    float dh[H], es[H];
    #pragma unroll
    for (int hh = 0; hh < H; ++hh) {
        dh[hh] = darr[(size_t)iG * H + hh];
        float e = sarr[(size_t)iG * H + hh] + dh[hh];
        es[hh] = fmaxf(e, 0.2f * e);
    }

    if (deg <= 64) {
        int srcL = (lane < deg) ? col[start + lane] : 0;
        float pl[H];
        if (lane < deg) {
            #pragma unroll
            for (int hh = 0; hh < H; ++hh) {
                float e = sb[(size_t)srcL * H + hh] + dh[hh];
                pl[hh] = __expf(fmaxf(e, 0.2f * e));
            }
        } else {
            #pragma unroll
            for (int hh = 0; hh < H; ++hh) pl[hh] = 0.f;
        }
        float zh[H];
        #pragma unroll
        for (int hh = 0; hh < H; ++hh) zh[hh] = pl[hh];
        #pragma unroll
        for (int hh = 0; hh < H; ++hh)
            for (int o = 32; o >= 1; o >>= 1)
                zh[hh] += __shfl_xor(zh[hh], o, 64);
        float av[H], sf[H];
        #pragma unroll
        for (int hh = 0; hh < H; ++hh) {
            float se = __expf(es[hh]);
            float invz = 1.f / (zh[hh] + se + 1e-16f);
            sf[hh] = se * invz;
            av[hh] = pl[hh] * invz;
        }
        if (lane < deg) store_alpha<H>(A, (size_t)(start + lane), av);
        if (lane == 0) store_alpha<H>(aselfA, (size_t)iG, sf);
        return;
    }

    // deg > 64: 2-pass (no max)
    float zh[H];
    #pragma unroll
    for (int hh = 0; hh < H; ++hh) zh[hh] = 0.f;
    for (int base = start; base < end; base += 64) {
        int idx = base + lane;
        if (idx < end) {
            int src = col[idx];
            #pragma unroll
            for (int hh = 0; hh < H; ++hh) {
                float e = sb[(size_t)src * H + hh] + dh[hh];
                e = fmaxf(e, 0.2f * e);
                zh[hh] += __expf(e);
            }
        }
    }
    #pragma unroll
    for (int hh = 0; hh < H; ++hh)
        for (int o = 32; o >= 1; o >>= 1)
            zh[hh] += __shfl_xor(zh[hh], o, 64);
    float invz[H], sf[H];
    #pragma unroll
    for (int hh = 0; hh < H; ++hh) {
        float se = __expf(es[hh]);
        invz[hh] = 1.f / (zh[hh] + se + 1e-16f);
        sf[hh] = se * invz[hh];
    }
    if (lane == 0) store_alpha<H>(aselfA, (size_t)iG, sf);
    for (int base = start; base < end; base += 64) {
        int idx = base + lane;
        if (idx < end) {
            int src = col[idx];
            float av[H];
            #pragma unroll
            for (int hh = 0; hh < H; ++hh) {
                float e = sb[(size_t)src * H + hh] + dh[hh];
                e = fmaxf(e, 0.2f * e);
                av[hh] = __expf(e) * invz[hh];
            }
            store_alpha<H>(A, (size_t)idx, av);
        }
    }
}

// ---------------- alpha kernel: softmax only, no LDS, grid-stride persistent ----------------
template<int H>
__global__ __launch_bounds__(256) void alpha_kernel(const float* __restrict__ sarr,
                                                    const float* __restrict__ darr,
                                                    const int* __restrict__ roff,
                                                    const int* __restrict__ col,
                                                    __half* __restrict__ A,
                                                    __half* __restrict__ aselfA, int N)
{
    const int n2 = 2 * N;
    const int lane = threadIdx.x & 63;
    const int g = lane >> 5, l = lane & 31;
    const int nw  = (gridDim.x * 256) >> 6;
    const int wv0 = (blockIdx.x * 256 + threadIdx.x) >> 6;
    const int npair = (n2 + 1) >> 1;

    for (int pr = wv0; pr < npair; pr += nw) {
        const int i0 = pr * 2;
        const bool nval = (i0 + g) < n2;
        const int iN = nval ? (i0 + g) : (n2 - 1);
        const int start = roff[iN], end = roff[iN + 1];
        const int deg = nval ? (end - start) : 0;
        const int degO = __shfl_xor(deg, 32, 64);

        if (max(deg, degO) <= 32) {
            const int side = (iN >= N) ? 1 : 0;
            const float* sb = sarr + (size_t)side * N * H;
            float dh[H], es[H];
            if constexpr (H == 4) {
                float4 dv = *reinterpret_cast<const float4*>(darr + (size_t)iN * 4);
                float4 sv = *reinterpret_cast<const float4*>(sarr + (size_t)iN * 4);
                dh[0] = dv.x; dh[1] = dv.y; dh[2] = dv.z; dh[3] = dv.w;
                float ev[4] = {sv.x + dv.x, sv.y + dv.y, sv.z + dv.z, sv.w + dv.w};
                #pragma unroll
                for (int hh = 0; hh < 4; ++hh) es[hh] = fmaxf(ev[hh], 0.2f * ev[hh]);
            } else {
                #pragma unroll
                for (int hh = 0; hh < H; ++hh) {
                    dh[hh] = darr[(size_t)iN * H + hh];
                    float e = sarr[(size_t)iN * H + hh] + dh[hh];
                    es[hh] = fmaxf(e, 0.2f * e);
                }
            }
            int srcL = (l < deg) ? col[start + l] : 0;
            float pl[H];
            if (l < deg) {
                if constexpr (H == 4) {
                    float4 sv = *reinterpret_cast<const float4*>(sb + (size_t)srcL * 4);
                    float ee[4] = {sv.x + dh[0], sv.y + dh[1], sv.z + dh[2], sv.w + dh[3]};
                    #pragma unroll
                    for (int hh = 0; hh < 4; ++hh) pl[hh] = __expf(fmaxf(ee[hh], 0.2f * ee[hh]));
                } else {
                    #pragma unroll
                    for (int hh = 0; hh < H; ++hh) {
                        float e = sb[(size_t)srcL * H + hh] + dh[hh];
                        pl[hh] = __expf(fmaxf(e, 0.2f * e));
                    }
                }
            } else {
                #pragma unroll
                for (int hh = 0; hh < H; ++hh) pl[hh] = 0.f;
            }
            float zh[H];
            #pragma unroll
            for (int hh = 0; hh < H; ++hh) zh[hh] = pl[hh];
            #pragma unroll
            for (int hh = 0; hh < H; ++hh)
                #pragma unroll
                for (int o = 16; o >= 1; o >>= 1)
                    zh[hh] += __shfl_xor(zh[hh], o, 64);   // stays within 32-lane group
            float av[H], sf[H];
            #pragma unroll
            for (int hh = 0; hh < H; ++hh) {
                float se = __expf(es[hh]);
                float invz = 1.f / (zh[hh] + se + 1e-16f);
                sf[hh] = se * invz;
                av[hh] = pl[hh] * invz;
            }
            if (l < deg) store_alpha<H>(A, (size_t)(start + l), av);
            if (l == 0 && nval) store_alpha<H>(aselfA, (size_t)iN, sf);
        } else {
            for (int nd = 0; nd < 2; ++nd) {
                int i = i0 + nd;
                if (i >= n2) break;
                int sd2 = (i >= N) ? 1 : 0;
                alpha_one_fullwave<H>(i, lane, sarr, sarr + (size_t)sd2 * N * H, darr,
                                      roff, col, A, aselfA);
            }
        }
    }
}

// ---------------- gather kernel: TWO nodes per wave (32 lanes each) -- r10-proven form ----
// r11's 1-node/wave regressed (preamble ~3.4x a gather round; doubling iteration count
// dominated). This is the r10 structure + bias hoisted to registers (thread-constant)
// and roff loaded as int2 (one load).
template<int C, int H, bool ELU, bool OUTH>
__global__ __launch_bounds__(256) void gather_kernel(const __half* __restrict__ hm,
                                                     const __half* __restrict__ hp,
                                                     const __half* __restrict__ A,
                                                     const __half* __restrict__ aselfA,
                                                     const int* __restrict__ roff,
                                                     const int* __restrict__ col,
                                                     const float* __restrict__ bias_m,
                                                     const float* __restrict__ bias_p,
                                                     void* __restrict__ out_m,
                                                     void* __restrict__ out_p, int N)
{
    constexpr int CH  = C / H;
    constexpr int LRd = C / 8;        // lanes per row (16 for C=128, 8 for C=64)
    constexpr int EPd = 32 / LRd;     // edges in parallel per node (2 or 4)
    const int n2 = 2 * N;
    const int lane = threadIdx.x & 63;
    const int g = lane >> 5, l = lane & 31;
    const int sub = l / LRd, q = l % LRd;
    const int c0 = q * 8;
    const int hd = c0 / CH;
    const int nw  = (gridDim.x * 256) >> 6;
    const int wv0 = (blockIdx.x * 256 + threadIdx.x) >> 6;
    const int npair = (n2 + 1) >> 1;

    // hoisted bias (thread-constant)
    float4 bm0 = *reinterpret_cast<const float4*>(bias_m + c0);
    float4 bm1 = *reinterpret_cast<const float4*>(bias_m + c0 + 4);
    float4 bp0 = *reinterpret_cast<const float4*>(bias_p + c0);
    float4 bp1 = *reinterpret_cast<const float4*>(bias_p + c0 + 4);

    for (int pr = wv0; pr < npair; pr += nw) {
        const int i0 = pr * 2;
        const bool nval = (i0 + g) < n2;
        const int iN = nval ? (i0 + g) : (n2 - 1);
        const int side = (iN >= N) ? 1 : 0;
        const int lN = iN - side * N;
        const __half* hf = side ? hp : hm;
        const int2 ro = *reinterpret_cast<const int2*>(roff + iN);
        const int start = ro.x;
        const int deg = ro.y - ro.x;

        float acc[8];
        #pragma unroll
        for (int j = 0; j < 8; ++j) acc[j] = 0.f;
        if (sub == 0) {
            uint4 r = *reinterpret_cast<const uint4*>(hf + (size_t)lN * C + c0);
            float4 lo = cvt_h4(make_uint2(r.x, r.y));
            float4 hi = cvt_h4(make_uint2(r.z, r.w));
            float a = __half2float(aselfA[(size_t)iN * H + hd]);
            acc[0] = a * lo.x; acc[1] = a * lo.y; acc[2] = a * lo.z; acc[3] = a * lo.w;
            acc[4] = a * hi.x; acc[5] = a * hi.y; acc[6] = a * hi.z; acc[7] = a * hi.w;
        }
        int t = sub;
#define GSTEP(U)                                                                     \
        while (t + (U - 1) * EPd < deg) {                                            \
            int ss[U]; float aa[U]; uint4 rr[U];                                     \
            _Pragma("unroll")                                                        \
            for (int u = 0; u < U; ++u) {                                            \
                int e = start + t + u * EPd;                                         \
                ss[u] = col[e];                                                      \
                aa[u] = __half2float(A[(size_t)e * H + hd]);                         \
            }                                                                        \
            _Pragma("unroll")                                                        \
            for (int u = 0; u < U; ++u)                                              \
                rr[u] = *reinterpret_cast<const uint4*>(hf + (size_t)ss[u] * C + c0); \
            _Pragma("unroll")                                                        \
            for (int u = 0; u < U; ++u) {                                            \
                float4 lo = cvt_h4(make_uint2(rr[u].x, rr[u].y));                    \
                float4 hi = cvt_h4(make_uint2(rr[u].z, rr[u].w));                    \
                acc[0] = fmaf(aa[u], lo.x, acc[0]);                                  \
                acc[1] = fmaf(aa[u], lo.y, acc[1]);                                  \
                acc[2] = fmaf(aa[u], lo.z, acc[2]);                                  \
                acc[3] = fmaf(aa[u], lo.w, acc[3]);                                  \
                acc[4] = fmaf(aa[u], hi.x, acc[4]);                                  \
                acc[5] = fmaf(aa[u], hi.y, acc[5]);                                  \
                acc[6] = fmaf(aa[u], hi.z, acc[6]);                                  \
                acc[7] = fmaf(aa[u], hi.w, acc[7]);                                  \
            }                                                                        \
            t += U * EPd;                                                            \
        }
        GSTEP(4)
        GSTEP(2)
        GSTEP(1)
#undef GSTEP
        // cross-sub reduce (offsets stay within the 32-lane group)
        #pragma unroll
        for (int o = LRd; o < 32; o <<= 1) {
            #pragma unroll
            for (int j = 0; j < 8; ++j) acc[j] += __shfl_xor(acc[j], o, 64);
        }
        if (sub == 0 && nval) {
            float4 b0 = side ? bp0 : bm0;
            float4 b1 = side ? bp1 : bm1;
            float v[8] = {acc[0] + b0.x, acc[1] + b0.y, acc[2] + b0.z, acc[3] + b0.w,
                          acc[4] + b1.x, acc[5] + b1.y, acc[6] + b1.z, acc[7] + b1.w};
            if constexpr (ELU) {
                #pragma unroll
                for (int j = 0; j < 8; ++j) v[j] = (v[j] > 0.f) ? v[j] : (__expf(v[j]) - 1.f);
            }
            if constexpr (OUTH) {
                __half* outS = (__half*)(side ? out_p : out_m);
                uint4 w;
                w.x = pack_h2(v[0], v[1]); w.y = pack_h2(v[2], v[3]);
                w.z = pack_h2(v[4], v[5]); w.w = pack_h2(v[6], v[7]);
                *reinterpret_cast<uint4*>(outS + (size_t)lN * C + c0) = w;
            } else {
                float* outS = (float*)(side ? out_p : out_m);
                float* po = outS + (size_t)lN * C + c0;
                *reinterpret_cast<float4*>(po)     = make_float4(v[0], v[1], v[2], v[3]);
                *reinterpret_cast<float4*>(po + 4) = make_float4(v[4], v[5], v[6], v[7]);
            }
        }
    }
}

// ---------------- edge logits: fp16 z, 8 lanes/edge (uint4), 2x unrolled ----------------
__global__ __launch_bounds__(256) void logits_kernel(const __half* __restrict__ zp,
                                                     const __half* __restrict__ zm,
                                                     const int* __restrict__ prov,
                                                     const int* __restrict__ memb,
                                                     float* __restrict__ outv, int e)
{
    const int nw   = (gridDim.x * 256) >> 6;
    const int wv   = (blockIdx.x * 256 + threadIdx.x) >> 6;
    const int lane = threadIdx.x & 63;
    const int g = lane >> 3, q = lane & 7;     // 8 edges/wave, 8 lanes/edge, 8 ch/lane
    const int c0 = q * 8;
    for (int base = wv * 16; base < e; base += nw * 16) {
        int e1 = base + g, e2 = base + 8 + g;
        bool v1 = e1 < e, v2 = e2 < e;
        int i1 = v1 ? e1 : (e - 1), i2 = v2 ? e2 : (e - 1);
        int p1 = prov[i1], m1 = memb[i1];
        int p2 = prov[i2], m2 = memb[i2];
        uint4 a1 = *reinterpret_cast<const uint4*>(zp + (size_t)p1 * 64 + c0);
        uint4 b1 = *reinterpret_cast<const uint4*>(zm + (size_t)m1 * 64 + c0);
        uint4 a2 = *reinterpret_cast<const uint4*>(zp + (size_t)p2 * 64 + c0);
        uint4 b2 = *reinterpret_cast<const uint4*>(zm + (size_t)m2 * 64 + c0);
        float4 al1 = cvt_h4(make_uint2(a1.x, a1.y)), ah1 = cvt_h4(make_uint2(a1.z, a1.w));
        float4 bl1 = cvt_h4(make_uint2(b1.x, b1.y)), bh1 = cvt_h4(make_uint2(b1.z, b1.w));
        float4 al2 = cvt_h4(make_uint2(a2.x, a2.y)), ah2 = cvt_h4(make_uint2(a2.z, a2.w));
        float4 bl2 = cvt_h4(make_uint2(b2.x, b2.y)), bh2 = cvt_h4(make_uint2(b2.z, b2.w));
        float s1 = al1.x * bl1.x + al1.y * bl1.y + al1.z * bl1.z + al1.w * bl1.w
                 + ah1.x * bh1.x + ah1.y * bh1.y + ah1.z * bh1.z + ah1.w * bh1.w;
        float s2 = al2.x * bl2.x + al2.y * bl2.y + al2.z * bl2.z + al2.w * bl2.w
                 + ah2.x * bh2.x + ah2.y * bh2.y + ah2.z * bh2.z + ah2.w * bh2.w;
        #pragma unroll
        for (int o = 1; o < 8; o <<= 1) {
            s1 += __shfl_xor(s1, o, 64);
            s2 += __shfl_xor(s2, o, 64);
        }
        if (q == 0) {
            if (v1) outv[e1] = s1;
            if (v2) outv[e2] = s2;
        }
    }
}

// ---------------- launch ----------------
extern "C" void kernel_launch(void* const* d_in, const int* in_sizes, int n_in,
                              void* d_out, int out_size, void* d_ws, size_t ws_size,
                              hipStream_t stream)
{
    const int N_ = in_sizes[0] / 128;
    const int E_ = in_sizes[2] / 2;

    const float* x_member   = (const float*)d_in[0];
    const float* x_provider = (const float*)d_in[1];
    const int*   prov = (const int*)d_in[2];
    const int*   memb = prov + E_;
    const float* W1_m = (const float*)d_in[3];
    const float* a_src1_m = (const float*)d_in[4];
    const float* a_dst1_m = (const float*)d_in[5];
    const float* b1_m = (const float*)d_in[6];
    const float* W2_m = (const float*)d_in[7];
    const float* a_src2_m = (const float*)d_in[8];
    const float* a_dst2_m = (const float*)d_in[9];
    const float* b2_m = (const float*)d_in[10];
    const float* W1_p = (const float*)d_in[11];
    const float* a_src1_p = (const float*)d_in[12];
    const float* a_dst1_p = (const float*)d_in[13];
    const float* b1_p = (const float*)d_in[14];
    const float* W2_p = (const float*)d_in[15];
    const float* a_src2_p = (const float*)d_in[16];
    const float* a_dst2_p = (const float*)d_in[17];
    const float* b2_p = (const float*)d_in[18];
    const float* Wd_m = (const float*)d_in[19];
    const float* bd_m = (const float*)d_in[20];
    const float* Wd_p = (const float*)d_in[21];
    const float* bd_p = (const float*)d_in[22];

    const int n2 = 2 * N_;
    const int NB = (n2 + 127) >> BSH;           // 782 buckets

    char* p = (char*)d_ws;
    auto alloc = [&](size_t bytes) { void* q = (void*)p; p += (bytes + 255) & ~(size_t)255; return q; };
    // h1m/h1p contiguous: bstore (16 MB) overlays both (25.6 MB) during CSR build.
    __half* h1m   = (__half*)alloc((size_t)N_ * 128 * 2);
    __half* h1p   = (__half*)alloc((size_t)N_ * 128 * 2);
    __half* xm16m = (__half*)alloc((size_t)N_ * 128 * 2);
    __half* xm16p = (__half*)alloc((size_t)N_ * 128 * 2);
    __half* zm16  = (__half*)alloc((size_t)N_ * 64 * 2);   // layer-2 output; alpha1 overlay
    __half* zp16  = (__half*)alloc((size_t)N_ * 64 * 2);
    float* s1     = (float*)alloc((size_t)n2 * 4 * 4);     // also reused for layer-2 s (H=1)
    float* d1     = (float*)alloc((size_t)n2 * 4 * 4);
    __half* alpha2= (__half*)alloc((size_t)2 * E_ * 2);    // layer-2 per-edge alpha (H=1)
    __half* aselfH= (__half*)alloc((size_t)n2 * 4 * 2);    // per-node self alpha (H<=4)
    int*   bcnt   = (int*)alloc((size_t)NB * 4);
    int*   bbase  = (int*)alloc(1024 * 4);
    int*   roff2  = (int*)alloc((size_t)(n2 + 1) * 4);
    int*   colA   = (int*)alloc((size_t)2 * E_ * 4);
    // prepped fp16 weights (fragment-ordered, + folded sd columns)
    f16_t* B1m = (f16_t*)alloc((size_t)(128 + 16) * 128 * 2);
    f16_t* B1p = (f16_t*)alloc((size_t)(128 + 16) * 128 * 2);
    f16_t* B2m = (f16_t*)alloc((size_t)(64 + 16) * 128 * 2);
    f16_t* B2p = (f16_t*)alloc((size_t)(64 + 16) * 128 * 2);
    f16_t* Bdm = (f16_t*)alloc((size_t)(128 + 16) * 64 * 2);
    f16_t* Bdp = (f16_t*)alloc((size_t)(128 + 16) * 64 * 2);
    __half* h2m = h1m;                           // overlay: h1 dead after gather1 (6.4 <= 12.8 MB)
    __half* h2p = h1p;
    int2*  bstore = (int2*)h1m;                  // overlay: dead before gemm1 writes h1
    __half* alpha1 = zm16;                       // overlay: zm16+zp16 (12.8 MB) dead until gather2;
                                                 // alpha1 = 2E*4 halves = 12.8 MB exactly

    // bucketed CSR build (both sides at once; dst ids: member v, provider N+v)
    hipMemsetAsync(bcnt, 0, (size_t)NB * 4, stream);
    bucket_scatter_kernel<<<(E_ + CHUNK_E - 1) / CHUNK_E, 256, 0, stream>>>(prov, memb, bcnt, bstore, E_, N_, NB);
    bucket_scan_kernel<<<1, 1024, 0, stream>>>(bcnt, bbase, roff2, NB, n2);
    bucket_build_kernel<<<NB, 256, 0, stream>>>(bcnt, bbase, bstore, roff2, colA, n2);

    // weight prep (tiny)
    prep_kernel<<<6, 256, 0, stream>>>(
        W1_m, a_src1_m, a_dst1_m, W1_p, a_src1_p, a_dst1_p,
        W2_m, a_src2_m, a_dst2_m, W2_p, a_src2_p, a_dst2_p,
        Wd_m, Wd_p, B1m, B1p, B2m, B2p, Bdm, Bdp);

    const dim3 gg((N_ + 127) / 128, 2);
    float* out = (float*)d_out;

    // layer 1: mfma gemm (sd folded into B) -> alpha -> gather
    mfma_gemm<128, 128, false, true, 4, false><<<gg, 256, 0, stream>>>(
        x_member, x_provider, B1m, B1p, nullptr, nullptr, s1, d1, h1m, h1p, N_);
    alpha_kernel<4><<<2048, 256, 0, stream>>>(s1, d1, roff2, colA, alpha1, aselfH, N_);
    gather_kernel<128, 4, true, true><<<2048, 256, 0, stream>>>(
        h1m, h1p, alpha1, aselfH, roff2, colA, b1_m, b1_p, xm16m, xm16p, N_);

    // layer 2: mfma gemm (sd folded, H=1) -> alpha -> gather
    mfma_gemm<128, 64, true, true, 1, false><<<gg, 256, 0, stream>>>(
        xm16m, xm16p, B2m, B2p, nullptr, nullptr, s1, d1, h2m, h2p, N_);
    alpha_kernel<1><<<2048, 256, 0, stream>>>(s1, d1, roff2, colA, alpha2, aselfH, N_);
    gather_kernel<64, 1, false, true><<<2048, 256, 0, stream>>>(
        h2m, h2p, alpha2, aselfH, roff2, colA, b2_m, b2_p, zm16, zp16, N_);

    // decoders (mfma, fp16 z input, fp32 out, +bias) + logits (fp16 z)
    mfma_gemm<64, 128, true, false, 0, true><<<gg, 256, 0, stream>>>(
        zm16, zp16, Bdm, Bdp, bd_m, bd_p, nullptr, nullptr,
        out, out + (size_t)N_ * 128, N_);
    logits_kernel<<<2048, 256, 0, stream>>>(zp16, zm16, prov, memb, out + (size_t)N_ * 128 * 2, E_);
}

// Round 13
// 440.329 us; speedup vs baseline: 1.1187x; 1.0400x over previous
//
#include <hip/hip_runtime.h>
#include <hip/hip_fp16.h>
#include <stdint.h>

typedef _Float16 f16_t;
typedef _Float16 f16x8 __attribute__((ext_vector_type(8)));
typedef float f32x4 __attribute__((ext_vector_type(4)));

// ---- helpers: fp16 pack/unpack ----
__device__ __forceinline__ unsigned int pack_h2(float a, float b) {
    return (unsigned int)__half_as_ushort(__float2half(a)) |
           ((unsigned int)__half_as_ushort(__float2half(b)) << 16);
}
__device__ __forceinline__ float4 cvt_h4(uint2 r) {
    __half2 h0 = *reinterpret_cast<__half2*>(&r.x);
    __half2 h1 = *reinterpret_cast<__half2*>(&r.y);
    float2 f0 = __half22float2(h0), f1 = __half22float2(h1);
    return make_float4(f0.x, f0.y, f1.x, f1.y);
}

// ---------------- weight prep: W[K][COUT] fp32 -> B fragment-ordered fp16 ----------------
// Layout: B[t][kb][lane][e]  (t = 16-col tile incl. sd tile, kb = 32-k block,
// lane = kg*16+col, e = 0..7; element = W[kb*32+kg*8+e][t*16+col]).
// sd fold: cols COUT..COUT+H-1 = W@asrc per head; COUT+H..COUT+2H-1 = W@adst; rest 0.
__global__ __launch_bounds__(256) void prep_kernel(
    const float* __restrict__ W1m, const float* __restrict__ as1m, const float* __restrict__ ad1m,
    const float* __restrict__ W1p, const float* __restrict__ as1p, const float* __restrict__ ad1p,
    const float* __restrict__ W2m, const float* __restrict__ as2m, const float* __restrict__ ad2m,
    const float* __restrict__ W2p, const float* __restrict__ as2p, const float* __restrict__ ad2p,
    const float* __restrict__ Wdm, const float* __restrict__ Wdp,
    f16_t* __restrict__ B1m, f16_t* __restrict__ B1p,
    f16_t* __restrict__ B2m, f16_t* __restrict__ B2p,
    f16_t* __restrict__ Bdm, f16_t* __restrict__ Bdp)
{
    const float *W = nullptr, *as = nullptr, *ad = nullptr;
    f16_t* B = nullptr; int K = 0, COUT = 0, H = 0;
    switch (blockIdx.x) {
        case 0: W = W1m; as = as1m; ad = ad1m; B = B1m; K = 128; COUT = 128; H = 4; break;
        case 1: W = W1p; as = as1p; ad = ad1p; B = B1p; K = 128; COUT = 128; H = 4; break;
        case 2: W = W2m; as = as2m; ad = ad2m; B = B2m; K = 128; COUT = 64;  H = 1; break;
        case 3: W = W2p; as = as2p; ad = ad2p; B = B2p; K = 128; COUT = 64;  H = 1; break;
        case 4: W = Wdm; B = Bdm; K = 64; COUT = 128; H = 0; break;
        case 5: W = Wdp; B = Bdp; K = 64; COUT = 128; H = 0; break;
    }
    const int KB = K / 32;
    const int TT = (COUT + 16) / 16;
    const int total = TT * KB * 512;              // == (COUT+16)*K
    for (int idx = threadIdx.x; idx < total; idx += 256) {
        int t    = idx / (KB * 512);
        int r    = idx - t * (KB * 512);
        int kb   = r >> 9;
        int r2   = r & 511;
        int lane = r2 >> 3, e = r2 & 7;
        int col  = lane & 15, kg = lane >> 4;
        int k    = kb * 32 + kg * 8 + e;
        int c    = t * 16 + col;
        float v = 0.f;
        if (c < COUT) {
            v = W[(size_t)k * COUT + c];
        } else {
            int ee = c - COUT;
            if (H > 0 && ee < 2 * H) {
                int h = (ee < H) ? ee : ee - H;
                const float* av = (ee < H) ? as : ad;
                int CH = COUT / H;
                for (int cc = 0; cc < CH; ++cc)
                    v += W[(size_t)k * COUT + h * CH + cc] * av[h * CH + cc];
            }
        }
        B[idx] = (f16_t)v;
    }
}

// ---------------- MFMA GEMM: out[n,COUT] = X[n,K] @ W  (+bias), fp32 acc ----------------
// 4 waves/block, each wave = 32 rows (2 A-frags) x COUT. No LDS. B fragment-ordered
// (coalesced 1-KB loads, shared across both row-frags). SDH>0: extra tile = s|d.
template<int K, int COUT, bool IN_HALF, bool OUT_HALF, int SDH, bool ADD_BIAS>
__global__ __launch_bounds__(256) void mfma_gemm(const void* __restrict__ X0,
                                                 const void* __restrict__ X1,
                                                 const f16_t* __restrict__ B0,
                                                 const f16_t* __restrict__ B1,
                                                 const float* __restrict__ b0,
                                                 const float* __restrict__ b1,
                                                 float* __restrict__ s_out,
                                                 float* __restrict__ d_out,
                                                 void* __restrict__ out0,
                                                 void* __restrict__ out1, int n)
{
    constexpr int NT = COUT / 16;                 // output col-tiles
    constexpr int TT = NT + ((SDH > 0) ? 1 : 0);  // + sd tile
    constexpr int KB = K / 32;

    const int side = blockIdx.y;
    const void*  Xv = side ? X1 : X0;
    const f16_t* B  = side ? B1 : B0;
    const float* bias = side ? b1 : b0;
    void* outp = side ? out1 : out0;

    const int wid  = threadIdx.x >> 6;
    const int lane = threadIdx.x & 63;
    const int r0 = blockIdx.x * 128 + wid * 32;
    if (r0 >= n) return;
    const int col = lane & 15;
    const int kg  = lane >> 4;                    // k-chunk 0..3 (8 f16 each)
    const int ar0 = min(r0 + col, n - 1);
    const int ar1 = min(r0 + 16 + col, n - 1);

    f32x4 acc[2][TT];
    #pragma unroll
    for (int h = 0; h < 2; ++h)
        #pragma unroll
        for (int t = 0; t < TT; ++t) acc[h][t] = (f32x4)0.f;

    #pragma unroll
    for (int kb = 0; kb < KB; ++kb) {
        f16x8 a0, a1;
        if constexpr (IN_HALF) {
            a0 = *reinterpret_cast<const f16x8*>((const f16_t*)Xv + (size_t)ar0 * K + kb * 32 + kg * 8);
            a1 = *reinterpret_cast<const f16x8*>((const f16_t*)Xv + (size_t)ar1 * K + kb * 32 + kg * 8);
        } else {
            const float* x0 = (const float*)Xv + (size_t)ar0 * K + kb * 32 + kg * 8;
            const float* x1 = (const float*)Xv + (size_t)ar1 * K + kb * 32 + kg * 8;
            float4 u0 = *reinterpret_cast<const float4*>(x0);
            float4 w0 = *reinterpret_cast<const float4*>(x0 + 4);
            float4 u1 = *reinterpret_cast<const float4*>(x1);
            float4 w1 = *reinterpret_cast<const float4*>(x1 + 4);
            a0[0] = (f16_t)u0.x; a0[1] = (f16_t)u0.y; a0[2] = (f16_t)u0.z; a0[3] = (f16_t)u0.w;
            a0[4] = (f16_t)w0.x; a0[5] = (f16_t)w0.y; a0[6] = (f16_t)w0.z; a0[7] = (f16_t)w0.w;
            a1[0] = (f16_t)u1.x; a1[1] = (f16_t)u1.y; a1[2] = (f16_t)u1.z; a1[3] = (f16_t)u1.w;
            a1[4] = (f16_t)w1.x; a1[5] = (f16_t)w1.y; a1[6] = (f16_t)w1.z; a1[7] = (f16_t)w1.w;
        }
        #pragma unroll
        for (int t = 0; t < TT; ++t) {
            f16x8 bf = *reinterpret_cast<const f16x8*>(B + ((size_t)(t * KB + kb) * 64 + lane) * 8);
            acc[0][t] = __builtin_amdgcn_mfma_f32_16x16x32_f16(a0, bf, acc[0][t], 0, 0, 0);
            acc[1][t] = __builtin_amdgcn_mfma_f32_16x16x32_f16(a1, bf, acc[1][t], 0, 0, 0);
        }
    }

    #pragma unroll
    for (int h = 0; h < 2; ++h) {
        const int rb = r0 + h * 16 + 4 * kg;      // this frag's 4 output rows
        #pragma unroll
        for (int t = 0; t < NT; ++t) {
            float bv = 0.f;
            if constexpr (ADD_BIAS) bv = bias[t * 16 + col];
            #pragma unroll
            for (int j = 0; j < 4; ++j) {
                int row = rb + j;
                if (row < n) {
                    float v = acc[h][t][j] + bv;
                    if constexpr (OUT_HALF)
                        ((__half*)outp)[(size_t)row * COUT + t * 16 + col] = __float2half(v);
                    else
                        ((float*)outp)[(size_t)row * COUT + t * 16 + col] = v;
                }
            }
        }
        if constexpr (SDH > 0) {
            #pragma unroll
            for (int j = 0; j < 4; ++j) {
                int row = rb + j;
                if (row < n) {
                    float v = acc[h][NT][j];
                    size_t gi = (size_t)(side ? n + row : row) * SDH;
                    if (col < SDH) s_out[gi + col] = v;
                    else if (col < 2 * SDH) d_out[gi + (col - SDH)] = v;
                }
            }
        }
    }
}

// ---------------- bucketed CSR build ----------------
#define BSH 7
#define BCAP 2560     // mean 2048 entries/bucket, +11 sigma headroom
#define CHUNK_E 4096  // edges per block (r10-proven; 1024 quadrupled per-block fixed cost
                      // -- 782-entry hist init + lbase sweep + 4x bcnt atomics -- net loss)

__global__ __launch_bounds__(256) void bucket_scatter_kernel(const int* __restrict__ prov,
                                                             const int* __restrict__ memb,
                                                             int* __restrict__ bcnt,
                                                             int2* __restrict__ bstore,
                                                             int e, int n, int nbuck)
{
    __shared__ int hist[1024];
    __shared__ int lbase[1024];
    const int tid = threadIdx.x;
    const int e0 = blockIdx.x * CHUNK_E;
    const int e1 = min(e, e0 + CHUNK_E);

    for (int i = tid; i < nbuck; i += 256) hist[i] = 0;
    __syncthreads();
    for (int t = e0 + tid; t < e1; t += 256) {
        int m = memb[t], p = prov[t];
        atomicAdd(&hist[m >> BSH], 1);
        atomicAdd(&hist[(n + p) >> BSH], 1);
    }
    __syncthreads();
    for (int i = tid; i < nbuck; i += 256) {
        int h = hist[i];
        lbase[i] = (h > 0) ? atomicAdd(&bcnt[i], h) : 0;
        hist[i] = 0;   // reuse as intra-block cursor
    }
    __syncthreads();
    for (int t = e0 + tid; t < e1; t += 256) {
        int m = memb[t], p = prov[t];
        int b1 = m >> BSH;
        int pos1 = lbase[b1] + atomicAdd(&hist[b1], 1);
        if (pos1 < BCAP) bstore[(size_t)b1 * BCAP + pos1] = make_int2(m, p);
        int d2 = n + p;
        int b2 = d2 >> BSH;
        int pos2 = lbase[b2] + atomicAdd(&hist[b2], 1);
        if (pos2 < BCAP) bstore[(size_t)b2 * BCAP + pos2] = make_int2(d2, m);
    }
}

__global__ __launch_bounds__(1024) void bucket_scan_kernel(const int* __restrict__ bcnt,
                                                           int* __restrict__ bbase,
                                                           int* __restrict__ roff,
                                                           int nb, int n2)
{
    __shared__ int tmp[1024];
    int tid = threadIdx.x;
    int v = (tid < nb) ? min(bcnt[tid], BCAP) : 0;
    tmp[tid] = v; __syncthreads();
    for (int o = 1; o < 1024; o <<= 1) {
        int x = (tid >= o) ? tmp[tid - o] : 0;
        __syncthreads();
        tmp[tid] += x;
        __syncthreads();
    }
    bbase[tid] = tmp[tid] - v;          // exclusive bucket base
    if (tid == 0) roff[n2] = tmp[1023]; // total == 2E
}

__global__ __launch_bounds__(256) void bucket_build_kernel(const int* __restrict__ bcnt,
                                                           const int* __restrict__ bbase,
                                                           const int2* __restrict__ bstore,
                                                           int* __restrict__ roff,
                                                           int* __restrict__ colA,
                                                           int n2)
{
    __shared__ int2 ent[BCAP];
    __shared__ int  colL[BCAP];
    __shared__ int  cnts[128], pref[128], curs[128];

    const int b = blockIdx.x, tid = threadIdx.x;
    const int node0 = b << BSH;
    const int cnt  = min(bcnt[b], BCAP);
    const int base = bbase[b];

    if (tid < 128) cnts[tid] = 0;
    __syncthreads();
    for (int i = tid; i < cnt; i += 256) {
        int2 v = bstore[(size_t)b * BCAP + i];
        ent[i] = v;
        atomicAdd(&cnts[v.x - node0], 1);
    }
    __syncthreads();
    if (tid < 128) pref[tid] = cnts[tid];
    __syncthreads();
    #pragma unroll
    for (int o = 1; o < 128; o <<= 1) {
        int x = 0;
        if (tid < 128 && tid >= o) x = pref[tid - o];
        __syncthreads();
        if (tid < 128) pref[tid] += x;
        __syncthreads();
    }
    if (tid < 128) {
        int node = node0 + tid;
        if (node < n2) roff[node] = base + pref[tid] - cnts[tid];
        curs[tid] = 0;
    }
    __syncthreads();
    for (int i = tid; i < cnt; i += 256) {
        int2 v = ent[i];
        int loc = v.x - node0;
        int slot = (pref[loc] - cnts[loc]) + atomicAdd(&curs[loc], 1);
        colL[slot] = v.y;
    }
    __syncthreads();
    for (int i = tid; i < cnt; i += 256) colA[base + i] = colL[i];
}

// ---------------- alpha store helpers ----------------
template<int H>
__device__ __forceinline__ void store_alpha(__half* __restrict__ A, size_t e, const float* a) {
    if constexpr (H == 4) {
        uint2 w; w.x = pack_h2(a[0], a[1]); w.y = pack_h2(a[2], a[3]);
        *reinterpret_cast<uint2*>(A + e * 4) = w;
    } else {
        A[e] = __float2half(a[0]);
    }
}

// ---------------- full-wave alpha fallback (deg<=64 / deg>64) ----------------
template<int H>
__device__ __forceinline__ void alpha_one_fullwave(int iG, int lane,
                                                   const float* __restrict__ sarr,
                                                   const float* __restrict__ sb,
                                                   const float* __restrict__ darr,
                                                   const int* __restrict__ roff,
                                                   const int* __restrict__ col,
                                                   __half* __restrict__ A,
                                                   __half* __restrict__ aselfA)
{
    const int start = roff[iG], end = roff[iG + 1];
    const int deg = end - start;

    float dh[H], es[H];
    #pragma unroll
    for (int hh = 0; hh < H; ++hh) {
        dh[hh] = darr[(size_t)iG * H + hh];
        float e = sarr[(size_t)iG * H + hh] + dh[hh];
        es[hh] = fmaxf(e, 0.2f * e);
    }

    if (deg <= 64) {
        int srcL = (lane < deg) ? col[start + lane] : 0;
        float pl[H];
        if (lane < deg) {
            #pragma unroll
            for (int hh = 0; hh < H; ++hh) {
                float e = sb[(size_t)srcL * H + hh] + dh[hh];
                pl[hh] = __expf(fmaxf(e, 0.2f * e));
            }
        } else {
            #pragma unroll
            for (int hh = 0; hh < H; ++hh) pl[hh] = 0.f;
        }
        float zh[H];
        #pragma unroll
        for (int hh = 0; hh < H; ++hh) zh[hh] = pl[hh];
        #pragma unroll
        for (int hh = 0; hh < H; ++hh)
            for (int o = 32; o >= 1; o >>= 1)
                zh[hh] += __shfl_xor(zh[hh], o, 64);
        float av[H], sf[H];
        #pragma unroll
        for (int hh = 0; hh < H; ++hh) {
            float se = __expf(es[hh]);
            float invz = 1.f / (zh[hh] + se + 1e-16f);
            sf[hh] = se * invz;
            av[hh] = pl[hh] * invz;
        }
        if (lane < deg) store_alpha<H>(A, (size_t)(start + lane), av);
        if (lane == 0) store_alpha<H>(aselfA, (size_t)iG, sf);
        return;
    }

    // deg > 64: 2-pass (no max)
    float zh[H];
    #pragma unroll
    for (int hh = 0; hh < H; ++hh) zh[hh] = 0.f;
    for (int base = start; base < end; base += 64) {
        int idx = base + lane;
        if (idx < end) {
            int src = col[idx];
            #pragma unroll
            for (int hh = 0; hh < H; ++hh) {
                float e = sb[(size_t)src * H + hh] + dh[hh];
                e = fmaxf(e, 0.2f * e);
                zh[hh] += __expf(e);
            }
        }
    }
    #pragma unroll
    for (int hh = 0; hh < H; ++hh)
        for (int o = 32; o >= 1; o >>= 1)
            zh[hh] += __shfl_xor(zh[hh], o, 64);
    float invz[H], sf[H];
    #pragma unroll
    for (int hh = 0; hh < H; ++hh) {
        float se = __expf(es[hh]);
        invz[hh] = 1.f / (zh[hh] + se + 1e-16f);
        sf[hh] = se * invz[hh];
    }
    if (lane == 0) store_alpha<H>(aselfA, (size_t)iG, sf);
    for (int base = start; base < end; base += 64) {
        int idx = base + lane;
        if (idx < end) {
            int src = col[idx];
            float av[H];
            #pragma unroll
            for (int hh = 0; hh < H; ++hh) {
                float e = sb[(size_t)src * H + hh] + dh[hh];
                e = fmaxf(e, 0.2f * e);
                av[hh] = __expf(e) * invz[hh];
            }
            store_alpha<H>(A, (size_t)idx, av);
        }
    }
}

// ---------------- alpha kernel: softmax only, no LDS, grid-stride persistent ----------------
template<int H>
__global__ __launch_bounds__(256) void alpha_kernel(const float* __restrict__ sarr,
                                                    const float* __restrict__ darr,
                                                    const int* __restrict__ roff,
                                                    const int* __restrict__ col,
                                                    __half* __restrict__ A,
                                                    __half* __restrict__ aselfA, int N)
{
    const int n2 = 2 * N;
    const int lane = threadIdx.x & 63;
    const int g = lane >> 5, l = lane & 31;
    const int nw  = (gridDim.x * 256) >> 6;
    const int wv0 = (blockIdx.x * 256 + threadIdx.x) >> 6;
    const int npair = (n2 + 1) >> 1;

    for (int pr = wv0; pr < npair; pr += nw) {
        const int i0 = pr * 2;
        const bool nval = (i0 + g) < n2;
        const int iN = nval ? (i0 + g) : (n2 - 1);
        const int2 ro = *reinterpret_cast<const int2*>(roff + iN);
        const int start = ro.x;
        const int deg = nval ? (ro.y - ro.x) : 0;
        const int degO = __shfl_xor(deg, 32, 64);

        if (max(deg, degO) <= 32) {
            const int side = (iN >= N) ? 1 : 0;
            const float* sb = sarr + (size_t)side * N * H;
            float dh[H], es[H];
            if constexpr (H == 4) {
                float4 dv = *reinterpret_cast<const float4*>(darr + (size_t)iN * 4);
                float4 sv = *reinterpret_cast<const float4*>(sarr + (size_t)iN * 4);
                dh[0] = dv.x; dh[1] = dv.y; dh[2] = dv.z; dh[3] = dv.w;
                float ev[4] = {sv.x + dv.x, sv.y + dv.y, sv.z + dv.z, sv.w + dv.w};
                #pragma unroll
                for (int hh = 0; hh < 4; ++hh) es[hh] = fmaxf(ev[hh], 0.2f * ev[hh]);
            } else {
                #pragma unroll
                for (int hh = 0; hh < H; ++hh) {
                    dh[hh] = darr[(size_t)iN * H + hh];
                    float e = sarr[(size_t)iN * H + hh] + dh[hh];
                    es[hh] = fmaxf(e, 0.2f * e);
                }
            }
            int srcL = (l < deg) ? col[start + l] : 0;
            float pl[H];
            if (l < deg) {
                if constexpr (H == 4) {
                    float4 sv = *reinterpret_cast<const float4*>(sb + (size_t)srcL * 4);
                    float ee[4] = {sv.x + dh[0], sv.y + dh[1], sv.z + dh[2], sv.w + dh[3]};
                    #pragma unroll
                    for (int hh = 0; hh < 4; ++hh) pl[hh] = __expf(fmaxf(ee[hh], 0.2f * ee[hh]));
                } else {
                    #pragma unroll
                    for (int hh = 0; hh < H; ++hh) {
                        float e = sb[(size_t)srcL * H + hh] + dh[hh];
                        pl[hh] = __expf(fmaxf(e, 0.2f * e));
                    }
                }
            } else {
                #pragma unroll
                for (int hh = 0; hh < H; ++hh) pl[hh] = 0.f;
            }
            float zh[H];
            #pragma unroll
            for (int hh = 0; hh < H; ++hh) zh[hh] = pl[hh];
            #pragma unroll
            for (int hh = 0; hh < H; ++hh)
                #pragma unroll
                for (int o = 16; o >= 1; o >>= 1)
                    zh[hh] += __shfl_xor(zh[hh], o, 64);   // stays within 32-lane group
            float av[H], sf[H];
            #pragma unroll
            for (int hh = 0; hh < H; ++hh) {
                float se = __expf(es[hh]);
                float invz = 1.f / (zh[hh] + se + 1e-16f);
                sf[hh] = se * invz;
                av[hh] = pl[hh] * invz;
            }
            if (l < deg) store_alpha<H>(A, (size_t)(start + l), av);
            if (l == 0 && nval) store_alpha<H>(aselfA, (size_t)iN, sf);
        } else {
            for (int nd = 0; nd < 2; ++nd) {
                int i = i0 + nd;
                if (i >= n2) break;
                int sd2 = (i >= N) ? 1 : 0;
                alpha_one_fullwave<H>(i, lane, sarr, sarr + (size_t)sd2 * N * H, darr,
                                      roff, col, A, aselfA);
            }
        }
    }
}

// ---------------- gather kernel: TWO nodes per wave (32 lanes each) -- r12-proven form ----
template<int C, int H, bool ELU, bool OUTH>
__global__ __launch_bounds__(256) void gather_kernel(const __half* __restrict__ hm,
                                                     const __half* __restrict__ hp,
                                                     const __half* __restrict__ A,
                                                     const __half* __restrict__ aselfA,
                                                     const int* __restrict__ roff,
                                                     const int* __restrict__ col,
                                                     const float* __restrict__ bias_m,
                                                     const float* __restrict__ bias_p,
                                                     void* __restrict__ out_m,
                                                     void* __restrict__ out_p, int N)
{
    constexpr int CH  = C / H;
    constexpr int LRd = C / 8;        // lanes per row (16 for C=128, 8 for C=64)
    constexpr int EPd = 32 / LRd;     // edges in parallel per node (2 or 4)
    const int n2 = 2 * N;
    const int lane = threadIdx.x & 63;
    const int g = lane >> 5, l = lane & 31;
    const int sub = l / LRd, q = l % LRd;
    const int c0 = q * 8;
    const int hd = c0 / CH;
    const int nw  = (gridDim.x * 256) >> 6;
    const int wv0 = (blockIdx.x * 256 + threadIdx.x) >> 6;
    const int npair = (n2 + 1) >> 1;

    // hoisted bias (thread-constant)
    float4 bm0 = *reinterpret_cast<const float4*>(bias_m + c0);
    float4 bm1 = *reinterpret_cast<const float4*>(bias_m + c0 + 4);
    float4 bp0 = *reinterpret_cast<const float4*>(bias_p + c0);
    float4 bp1 = *reinterpret_cast<const float4*>(bias_p + c0 + 4);

    for (int pr = wv0; pr < npair; pr += nw) {
        const int i0 = pr * 2;
        const bool nval = (i0 + g) < n2;
        const int iN = nval ? (i0 + g) : (n2 - 1);
        const int side = (iN >= N) ? 1 : 0;
        const int lN = iN - side * N;
        const __half* hf = side ? hp : hm;
        const int2 ro = *reinterpret_cast<const int2*>(roff + iN);
        const int start = ro.x;
        const int deg = ro.y - ro.x;

        float acc[8];
        #pragma unroll
        for (int j = 0; j < 8; ++j) acc[j] = 0.f;
        if (sub == 0) {
            uint4 r = *reinterpret_cast<const uint4*>(hf + (size_t)lN * C + c0);
            float4 lo = cvt_h4(make_uint2(r.x, r.y));
            float4 hi = cvt_h4(make_uint2(r.z, r.w));
            float a = __half2float(aselfA[(size_t)iN * H + hd]);
            acc[0] = a * lo.x; acc[1] = a * lo.y; acc[2] = a * lo.z; acc[3] = a * lo.w;
            acc[4] = a * hi.x; acc[5] = a * hi.y; acc[6] = a * hi.z; acc[7] = a * hi.w;
        }
        int t = sub;
#define GSTEP(U)                                                                     \
        while (t + (U - 1) * EPd < deg) {                                            \
            int ss[U]; float aa[U]; uint4 rr[U];                                     \
            _Pragma("unroll")                                                        \
            for (int u = 0; u < U; ++u) {                                            \
                int e = start + t + u * EPd;                                         \
                ss[u] = col[e];                                                      \
                aa[u] = __half2float(A[(size_t)e * H + hd]);                         \
            }                                                                        \
            _Pragma("unroll")                                                        \
            for (int u = 0; u < U; ++u)                                              \
                rr[u] = *reinterpret_cast<const uint4*>(hf + (size_t)ss[u] * C + c0); \
            _Pragma("unroll")                                                        \
            for (int u = 0; u < U; ++u) {                                            \
                float4 lo = cvt_h4(make_uint2(rr[u].x, rr[u].y));                    \
                float4 hi = cvt_h4(make_uint2(rr[u].z, rr[u].w));                    \
                acc[0] = fmaf(aa[u], lo.x, acc[0]);                                  \
                acc[1] = fmaf(aa[u], lo.y, acc[1]);                                  \
                acc[2] = fmaf(aa[u], lo.z, acc[2]);                                  \
                acc[3] = fmaf(aa[u], lo.w, acc[3]);                                  \
                acc[4] = fmaf(aa[u], hi.x, acc[4]);                                  \
                acc[5] = fmaf(aa[u], hi.y, acc[5]);                                  \
                acc[6] = fmaf(aa[u], hi.z, acc[6]);                                  \
                acc[7] = fmaf(aa[u], hi.w, acc[7]);                                  \
            }                                                                        \
            t += U * EPd;                                                            \
        }
        GSTEP(4)
        GSTEP(2)
        GSTEP(1)
#undef GSTEP
        // cross-sub reduce (offsets stay within the 32-lane group)
        #pragma unroll
        for (int o = LRd; o < 32; o <<= 1) {
            #pragma unroll
            for (int j = 0; j < 8; ++j) acc[j] += __shfl_xor(acc[j], o, 64);
        }
        if (sub == 0 && nval) {
            float4 b0 = side ? bp0 : bm0;
            float4 b1 = side ? bp1 : bm1;
            float v[8] = {acc[0] + b0.x, acc[1] + b0.y, acc[2] + b0.z, acc[3] + b0.w,
                          acc[4] + b1.x, acc[5] + b1.y, acc[6] + b1.z, acc[7] + b1.w};
            if constexpr (ELU) {
                #pragma unroll
                for (int j = 0; j < 8; ++j) v[j] = (v[j] > 0.f) ? v[j] : (__expf(v[j]) - 1.f);
            }
            if constexpr (OUTH) {
                __half* outS = (__half*)(side ? out_p : out_m);
                uint4 w;
                w.x = pack_h2(v[0], v[1]); w.y = pack_h2(v[2], v[3]);
                w.z = pack_h2(v[4], v[5]); w.w = pack_h2(v[6], v[7]);
                *reinterpret_cast<uint4*>(outS + (size_t)lN * C + c0) = w;
            } else {
                float* outS = (float*)(side ? out_p : out_m);
                float* po = outS + (size_t)lN * C + c0;
                *reinterpret_cast<float4*>(po)     = make_float4(v[0], v[1], v[2], v[3]);
                *reinterpret_cast<float4*>(po + 4) = make_float4(v[4], v[5], v[6], v[7]);
            }
        }
    }
}

// ---------------- edge logits: fp16 z, 8 lanes/edge (uint4), 2x unrolled ----------------
__global__ __launch_bounds__(256) void logits_kernel(const __half* __restrict__ zp,
                                                     const __half* __restrict__ zm,
                                                     const int* __restrict__ prov,
                                                     const int* __restrict__ memb,
                                                     float* __restrict__ outv, int e)
{
    const int nw   = (gridDim.x * 256) >> 6;
    const int wv   = (blockIdx.x * 256 + threadIdx.x) >> 6;
    const int lane = threadIdx.x & 63;
    const int g = lane >> 3, q = lane & 7;     // 8 edges/wave, 8 lanes/edge, 8 ch/lane
    const int c0 = q * 8;
    for (int base = wv * 16; base < e; base += nw * 16) {
        int e1 = base + g, e2 = base + 8 + g;
        bool v1 = e1 < e, v2 = e2 < e;
        int i1 = v1 ? e1 : (e - 1), i2 = v2 ? e2 : (e - 1);
        int p1 = prov[i1], m1 = memb[i1];
        int p2 = prov[i2], m2 = memb[i2];
        uint4 a1 = *reinterpret_cast<const uint4*>(zp + (size_t)p1 * 64 + c0);
        uint4 b1 = *reinterpret_cast<const uint4*>(zm + (size_t)m1 * 64 + c0);
        uint4 a2 = *reinterpret_cast<const uint4*>(zp + (size_t)p2 * 64 + c0);
        uint4 b2 = *reinterpret_cast<const uint4*>(zm + (size_t)m2 * 64 + c0);
        float4 al1 = cvt_h4(make_uint2(a1.x, a1.y)), ah1 = cvt_h4(make_uint2(a1.z, a1.w));
        float4 bl1 = cvt_h4(make_uint2(b1.x, b1.y)), bh1 = cvt_h4(make_uint2(b1.z, b1.w));
        float4 al2 = cvt_h4(make_uint2(a2.x, a2.y)), ah2 = cvt_h4(make_uint2(a2.z, a2.w));
        float4 bl2 = cvt_h4(make_uint2(b2.x, b2.y)), bh2 = cvt_h4(make_uint2(b2.z, b2.w));
        float s1 = al1.x * bl1.x + al1.y * bl1.y + al1.z * bl1.z + al1.w * bl1.w
                 + ah1.x * bh1.x + ah1.y * bh1.y + ah1.z * bh1.z + ah1.w * bh1.w;
        float s2 = al2.x * bl2.x + al2.y * bl2.y + al2.z * bl2.z + al2.w * bl2.w
                 + ah2.x * bh2.x + ah2.y * bh2.y + ah2.z * bh2.z + ah2.w * bh2.w;
        #pragma unroll
        for (int o = 1; o < 8; o <<= 1) {
            s1 += __shfl_xor(s1, o, 64);
            s2 += __shfl_xor(s2, o, 64);
        }
        if (q == 0) {
            if (v1) outv[e1] = s1;
            if (v2) outv[e2] = s2;
        }
    }
}

// ---------------- launch ----------------
extern "C" void kernel_launch(void* const* d_in, const int* in_sizes, int n_in,
                              void* d_out, int out_size, void* d_ws, size_t ws_size,
                              hipStream_t stream)
{
    const int N_ = in_sizes[0] / 128;
    const int E_ = in_sizes[2] / 2;

    const float* x_member   = (const float*)d_in[0];
    const float* x_provider = (const float*)d_in[1];
    const int*   prov = (const int*)d_in[2];
    const int*   memb = prov + E_;
    const float* W1_m = (const float*)d_in[3];
    const float* a_src1_m = (const float*)d_in[4];
    const float* a_dst1_m = (const float*)d_in[5];
    const float* b1_m = (const float*)d_in[6];
    const float* W2_m = (const float*)d_in[7];
    const float* a_src2_m = (const float*)d_in[8];
    const float* a_dst2_m = (const float*)d_in[9];
    const float* b2_m = (const float*)d_in[10];
    const float* W1_p = (const float*)d_in[11];
    const float* a_src1_p = (const float*)d_in[12];
    const float* a_dst1_p = (const float*)d_in[13];
    const float* b1_p = (const float*)d_in[14];
    const float* W2_p = (const float*)d_in[15];
    const float* a_src2_p = (const float*)d_in[16];
    const float* a_dst2_p = (const float*)d_in[17];
    const float* b2_p = (const float*)d_in[18];
    const float* Wd_m = (const float*)d_in[19];
    const float* bd_m = (const float*)d_in[20];
    const float* Wd_p = (const float*)d_in[21];
    const float* bd_p = (const float*)d_in[22];

    const int n2 = 2 * N_;
    const int NB = (n2 + 127) >> BSH;           // 782 buckets

    char* p = (char*)d_ws;
    auto alloc = [&](size_t bytes) { void* q = (void*)p; p += (bytes + 255) & ~(size_t)255; return q; };
    // h1m/h1p contiguous: bstore (16 MB) overlays both (25.6 MB) during CSR build.
    __half* h1m   = (__half*)alloc((size_t)N_ * 128 * 2);
    __half* h1p   = (__half*)alloc((size_t)N_ * 128 * 2);
    __half* xm16m = (__half*)alloc((size_t)N_ * 128 * 2);
    __half* xm16p = (__half*)alloc((size_t)N_ * 128 * 2);
    __half* zm16  = (__half*)alloc((size_t)N_ * 64 * 2);   // layer-2 output; alpha1 overlay
    __half* zp16  = (__half*)alloc((size_t)N_ * 64 * 2);
    float* s1     = (float*)alloc((size_t)n2 * 4 * 4);     // also reused for layer-2 s (H=1)
    float* d1     = (float*)alloc((size_t)n2 * 4 * 4);
    __half* alpha2= (__half*)alloc((size_t)2 * E_ * 2);    // layer-2 per-edge alpha (H=1)
    __half* aselfH= (__half*)alloc((size_t)n2 * 4 * 2);    // per-node self alpha (H<=4)
    int*   bcnt   = (int*)alloc((size_t)NB * 4);
    int*   bbase  = (int*)alloc(1024 * 4);
    int*   roff2  = (int*)alloc((size_t)(n2 + 1) * 4);
    int*   colA   = (int*)alloc((size_t)2 * E_ * 4);
    // prepped fp16 weights (fragment-ordered, + folded sd columns)
    f16_t* B1m = (f16_t*)alloc((size_t)(128 + 16) * 128 * 2);
    f16_t* B1p = (f16_t*)alloc((size_t)(128 + 16) * 128 * 2);
    f16_t* B2m = (f16_t*)alloc((size_t)(64 + 16) * 128 * 2);
    f16_t* B2p = (f16_t*)alloc((size_t)(64 + 16) * 128 * 2);
    f16_t* Bdm = (f16_t*)alloc((size_t)(128 + 16) * 64 * 2);
    f16_t* Bdp = (f16_t*)alloc((size_t)(128 + 16) * 64 * 2);
    __half* h2m = h1m;                           // overlay: h1 dead after gather1 (6.4 <= 12.8 MB)
    __half* h2p = h1p;
    int2*  bstore = (int2*)h1m;                  // overlay: dead before gemm1 writes h1
    __half* alpha1 = zm16;                       // overlay: zm16+zp16 (12.8 MB) dead until gather2;
                                                 // alpha1 = 2E*4 halves = 12.8 MB exactly

    // bucketed CSR build (both sides at once; dst ids: member v, provider N+v)
    hipMemsetAsync(bcnt, 0, (size_t)NB * 4, stream);
    bucket_scatter_kernel<<<(E_ + CHUNK_E - 1) / CHUNK_E, 256, 0, stream>>>(prov, memb, bcnt, bstore, E_, N_, NB);
    bucket_scan_kernel<<<1, 1024, 0, stream>>>(bcnt, bbase, roff2, NB, n2);
    bucket_build_kernel<<<NB, 256, 0, stream>>>(bcnt, bbase, bstore, roff2, colA, n2);

    // weight prep (tiny)
    prep_kernel<<<6, 256, 0, stream>>>(
        W1_m, a_src1_m, a_dst1_m, W1_p, a_src1_p, a_dst1_p,
        W2_m, a_src2_m, a_dst2_m, W2_p, a_src2_p, a_dst2_p,
        Wd_m, Wd_p, B1m, B1p, B2m, B2p, Bdm, Bdp);

    const dim3 gg((N_ + 127) / 128, 2);
    float* out = (float*)d_out;

    // layer 1: mfma gemm (sd folded into B) -> alpha -> gather
    mfma_gemm<128, 128, false, true, 4, false><<<gg, 256, 0, stream>>>(
        x_member, x_provider, B1m, B1p, nullptr, nullptr, s1, d1, h1m, h1p, N_);
    alpha_kernel<4><<<2048, 256, 0, stream>>>(s1, d1, roff2, colA, alpha1, aselfH, N_);
    gather_kernel<128, 4, true, true><<<2048, 256, 0, stream>>>(
        h1m, h1p, alpha1, aselfH, roff2, colA, b1_m, b1_p, xm16m, xm16p, N_);

    // layer 2: mfma gemm (sd folded, H=1) -> alpha -> gather
    mfma_gemm<128, 64, true, true, 1, false><<<gg, 256, 0, stream>>>(
        xm16m, xm16p, B2m, B2p, nullptr, nullptr, s1, d1, h2m, h2p, N_);
    alpha_kernel<1><<<2048, 256, 0, stream>>>(s1, d1, roff2, colA, alpha2, aselfH, N_);
    gather_kernel<64, 1, false, true><<<2048, 256, 0, stream>>>(
        h2m, h2p, alpha2, aselfH, roff2, colA, b2_m, b2_p, zm16, zp16, N_);

    // decoders (mfma, fp16 z input, fp32 out, +bias) + logits (fp16 z)
    mfma_gemm<64, 128, true, false, 0, true><<<gg, 256, 0, stream>>>(
        zm16, zp16, Bdm, Bdp, bd_m, bd_p, nullptr, nullptr,
        out, out + (size_t)N_ * 128, N_);
    logits_kernel<<<2048, 256, 0, stream>>>(zp16, zm16, prov, memb, out + (size_t)N_ * 128 * 2, E_);
}